// Round 19
// baseline (697.380 us; speedup 1.0000x reference)
//
#include <hip/hip_runtime.h>
#include <math.h>

static constexpr int Bn  = 64;    // batch
static constexpr int Cc  = 192;   // channels
static constexpr int Nn  = 784;   // H*W
static constexpr int C2c = 384;   // 2C
static constexpr int Kk  = 9;     // knn K
#define GAP_DELTA 1e-4f

typedef __attribute__((ext_vector_type(8))) short bf16x8;
typedef __attribute__((ext_vector_type(4))) float f32x4;

__device__ inline unsigned short f2bf(float f) {   // RNE f32 -> bf16
    unsigned int u = __float_as_uint(f);
    return (unsigned short)((u + 0x7FFFu + ((u >> 16) & 1u)) >> 16);
}

// ===========================================================================
// INDEX PATH — np-f32 bit-exact where values matter (fc1, norm, refine_amb).
// ===========================================================================

// fc1_np: BIT-CRITICAL — numpy-f32-exact (no FMA, ascending-c accumulation).
__global__ __launch_bounds__(256) void fc1_np(
    const float* __restrict__ x, const float* __restrict__ w,
    const float* __restrict__ bias,
    const float* __restrict__ gg, const float* __restrict__ bb_,
    const float* __restrict__ mm, const float* __restrict__ vv,
    float* __restrict__ xt)
{
    __shared__ float As[16][64];
    __shared__ float Bs[16][128];
    const int b   = blockIdx.z;
    const int n0  = blockIdx.x * 128;
    const int o0  = blockIdx.y * 64;
    const int tid = threadIdx.x;
    const int tx = tid & 15, ty = tid >> 4;
    const int lo = tid & 63, lk4 = tid >> 6;
    const int ln4 = tid & 15, lbk = tid >> 4;
    const float* xb = x + (size_t)b * Cc * Nn;

    float acc[4][8];
#pragma unroll
    for (int i = 0; i < 4; ++i)
#pragma unroll
        for (int j = 0; j < 8; ++j) acc[i][j] = 0.f;

    for (int kt = 0; kt < 12; ++kt) {               // c ascending: kt*16 + kk
        const int k0 = kt * 16;
        float4 av = *reinterpret_cast<const float4*>(&w[(size_t)(o0 + lo) * 192 + k0 + lk4 * 4]);
        As[lk4*4+0][lo] = av.x;
        As[lk4*4+1][lo] = av.y;
        As[lk4*4+2][lo] = av.z;
        As[lk4*4+3][lo] = av.w;
        const int na = n0 + ln4 * 4;
        const int nb = n0 + 64 + ln4 * 4;
        float4 b0 = make_float4(0.f, 0.f, 0.f, 0.f);
        float4 b1 = make_float4(0.f, 0.f, 0.f, 0.f);
        if (na < Nn) b0 = *reinterpret_cast<const float4*>(&xb[(size_t)(k0 + lbk) * Nn + na]);
        if (nb < Nn) b1 = *reinterpret_cast<const float4*>(&xb[(size_t)(k0 + lbk) * Nn + nb]);
        *reinterpret_cast<float4*>(&Bs[lbk][ln4*4])      = b0;
        *reinterpret_cast<float4*>(&Bs[lbk][64 + ln4*4]) = b1;
        __syncthreads();
#pragma unroll
        for (int kk = 0; kk < 16; ++kk) {
            float ar[4], br[8];
#pragma unroll
            for (int i = 0; i < 4; ++i) ar[i] = As[kk][ty*4+i];
#pragma unroll
            for (int j = 0; j < 4; ++j) br[j]     = Bs[kk][tx*4+j];
#pragma unroll
            for (int j = 0; j < 4; ++j) br[4 + j] = Bs[kk][64 + tx*4+j];
#pragma unroll
            for (int i = 0; i < 4; ++i)
#pragma unroll
                for (int j = 0; j < 8; ++j)
                    acc[i][j] = __fadd_rn(acc[i][j], __fmul_rn(ar[i], br[j]));
        }
        __syncthreads();
    }
    const int na = n0 + tx * 4;
    const int nb = n0 + 64 + tx * 4;
#pragma unroll
    for (int i = 0; i < 4; ++i) {
        const int o = o0 + ty * 4 + i;
        const float e  = __fadd_rn(vv[o], 1e-5f);
        const float r1 = __fsqrt_rn(e);
        const float rr = __fdiv_rn(1.f, r1);
        const float s  = __fmul_rn(gg[o], rr);
        const size_t rowb = ((size_t)b * Cc + o) * Nn;
        if (na < Nn) {
#pragma unroll
            for (int j = 0; j < 4; ++j) {
                const float h = __fadd_rn(acc[i][j], bias[o]);
                const float t = __fsub_rn(h, mm[o]);
                const float u = __fmul_rn(t, s);
                xt[rowb + na + j] = __fadd_rn(u, bb_[o]);
            }
        }
        if (nb < Nn) {
#pragma unroll
            for (int j = 0; j < 4; ++j) {
                const float h = __fadd_rn(acc[i][4 + j], bias[o]);
                const float t = __fsub_rn(h, mm[o]);
                const float u = __fmul_rn(t, s);
                xt[rowb + nb + j] = __fadd_rn(u, bb_[o]);
            }
        }
    }
}

// norm_np: numpy-exact. BIT-CRITICAL.
__global__ __launch_bounds__(256) void norm_np(
    const float* __restrict__ xt, float* __restrict__ xn, float* __restrict__ sq)
{
    const int idx = blockIdx.x * 256 + threadIdx.x;
    if (idx >= Bn * Nn) return;
    const int n = idx % Nn;
    const int b = idx / Nn;
    const float* p = xt + (size_t)b * Cc * Nn + n;

    float acc = 0.f;
    for (int c = 0; c < Cc; ++c) {
        const float v = p[(size_t)c * Nn];
        acc = __fadd_rn(acc, __fmul_rn(v, v));
    }
    float nrm = __fsqrt_rn(acc);
    nrm = fmaxf(nrm, 1e-12f);

    float* q = xn + (size_t)b * Cc * Nn + n;
    for (int c = 0; c < Cc; ++c)
        q[(size_t)c * Nn] = __fdiv_rn(p[(size_t)c * Nn], nrm);

    float sblk[2];
#pragma unroll
    for (int blk = 0; blk < 2; ++blk) {
        const int base = blk * 96;
        float r[8];
#pragma unroll
        for (int j = 0; j < 8; ++j) {
            const float xv = q[(size_t)(base + j) * Nn];
            r[j] = __fmul_rn(xv, xv);
        }
        for (int i = 8; i < 96; i += 8) {
#pragma unroll
            for (int j = 0; j < 8; ++j) {
                const float xv = q[(size_t)(base + i + j) * Nn];
                r[j] = __fadd_rn(r[j], __fmul_rn(xv, xv));
            }
        }
        sblk[blk] = __fadd_rn(__fadd_rn(__fadd_rn(r[0], r[1]), __fadd_rn(r[2], r[3])),
                              __fadd_rn(__fadd_rn(r[4], r[5]), __fadd_rn(r[6], r[7])));
    }
    sq[idx] = __fadd_rn(sblk[0], sblk[1]);
}

// xpose_bf: xn (col-major f32) -> split-bf16 row-major xnh/xnl[b][n][c].
// Tiled 64c x 64n through LDS; coalesced both ways. hi = bf16(x),
// lo = bf16(x - hi) (the subtraction is exact in f32).
__global__ __launch_bounds__(256) void xpose_bf(
    const float* __restrict__ xn, unsigned short* __restrict__ xnh,
    unsigned short* __restrict__ xnl)
{
    __shared__ float T[64][65];
    const int b  = blockIdx.z;
    const int c0 = blockIdx.y * 64;
    const int n0 = blockIdx.x * 64;
    const int tid = threadIdx.x;
    const int nl = tid & 63, cq = tid >> 6;

#pragma unroll
    for (int i = 0; i < 16; ++i) {
        const int c = c0 + cq + i * 4;
        const int n = n0 + nl;
        T[cq + i*4][nl] = (n < Nn) ? xn[((size_t)b * Cc + c) * Nn + n] : 0.f;
    }
    __syncthreads();
    const int nw = tid >> 2, cpart = tid & 3;
    const int n = n0 + nw;
    if (n < Nn) {
        unsigned short hbuf[16], lbuf[16];
#pragma unroll
        for (int j = 0; j < 16; ++j) {
            const float v = T[cpart * 16 + j][nw];
            const unsigned short h = f2bf(v);
            const float hf = __uint_as_float(((unsigned int)h) << 16);
            hbuf[j] = h;
            lbuf[j] = f2bf(__fsub_rn(v, hf));
        }
        unsigned short* dh = xnh + ((size_t)b * Nn + n) * Cc + c0 + cpart * 16;
        unsigned short* dl = xnl + ((size_t)b * Nn + n) * Cc + c0 + cpart * 16;
        *reinterpret_cast<bf16x8*>(&dh[0]) = *reinterpret_cast<bf16x8*>(&hbuf[0]);
        *reinterpret_cast<bf16x8*>(&dh[8]) = *reinterpret_cast<bf16x8*>(&hbuf[8]);
        *reinterpret_cast<bf16x8*>(&dl[0]) = *reinterpret_cast<bf16x8*>(&lbuf[0]);
        *reinterpret_cast<bf16x8*>(&dl[8]) = *reinterpret_cast<bf16x8*>(&lbuf[8]);
    }
}

// xpose_f32: xn (col-major) -> xnT[b][n][c] f32 row-major (bit-exact copy).
__global__ __launch_bounds__(256) void xpose_f32(
    const float* __restrict__ xn, float* __restrict__ xnT)
{
    __shared__ float T[64][65];
    const int b  = blockIdx.z;
    const int c0 = blockIdx.y * 64;
    const int n0 = blockIdx.x * 64;
    const int tid = threadIdx.x;
    const int nl = tid & 63, cq = tid >> 6;

#pragma unroll
    for (int i = 0; i < 16; ++i) {
        const int c = c0 + cq + i * 4;
        const int n = n0 + nl;
        T[cq + i*4][nl] = (n < Nn) ? xn[((size_t)b * Cc + c) * Nn + n] : 0.f;
    }
    __syncthreads();
    const int nw = tid >> 2, cpart = tid & 3;
    const int n = n0 + nw;
    if (n < Nn) {
        float* dst = xnT + ((size_t)b * Nn + n) * Cc + c0 + cpart * 16;
#pragma unroll
        for (int q = 0; q < 4; ++q) {
            float4 v = make_float4(T[cpart*16 + q*4 + 0][nw], T[cpart*16 + q*4 + 1][nw],
                                   T[cpart*16 + q*4 + 2][nw], T[cpart*16 + q*4 + 3][nw]);
            *reinterpret_cast<float4*>(&dst[q * 4]) = v;
        }
    }
}

// dist_mfma: fast filter via split-bf16 MFMA. dist = -(hh + hl + lh) dot.
// Upper-tri tiles only; mirror via LDS transpose. Layout mirrors fc2_mfma.
__global__ __launch_bounds__(256) void dist_mfma(
    const unsigned short* __restrict__ xnh, const unsigned short* __restrict__ xnl,
    float* __restrict__ dist, int bchunk)
{
    __shared__ float Ds[64][65];
    const int bt = blockIdx.x;             // 0..90 (upper-triangle tiles)
    int rt = 0, rem = bt;
    while (rem >= 13 - rt) { rem -= 13 - rt; ++rt; }
    const int mt = rt + rem;
    const int bc = blockIdx.y;             // 0..7
    const int b  = bchunk * 8 + bc;
    const int r0 = rt * 64, m0 = mt * 64;
    const int tid = threadIdx.x;
    const int wv = tid >> 6, l = tid & 63;
    const int lm = l & 15, lk = l >> 4;

    const int mcol = m0 + wv * 16 + lm;
    const int mcl  = (mcol < Nn) ? mcol : (Nn - 1);
    const unsigned short* mh = xnh + ((size_t)b * Nn + mcl) * Cc;
    const unsigned short* ml = xnl + ((size_t)b * Nn + mcl) * Cc;

    f32x4 acc[4];
#pragma unroll
    for (int mf = 0; mf < 4; ++mf) acc[mf] = (f32x4){0.f, 0.f, 0.f, 0.f};

#pragma unroll
    for (int ks = 0; ks < 6; ++ks) {
        const int k0 = ks * 32;
        bf16x8 bh = *reinterpret_cast<const bf16x8*>(&mh[k0 + lk * 8]);
        bf16x8 bl = *reinterpret_cast<const bf16x8*>(&ml[k0 + lk * 8]);
#pragma unroll
        for (int mf = 0; mf < 4; ++mf) {
            const int ar = r0 + mf * 16 + lm;
            const int arl = (ar < Nn) ? ar : (Nn - 1);
            bf16x8 ah = *reinterpret_cast<const bf16x8*>(
                &xnh[((size_t)b * Nn + arl) * Cc + k0 + lk * 8]);
            bf16x8 al = *reinterpret_cast<const bf16x8*>(
                &xnl[((size_t)b * Nn + arl) * Cc + k0 + lk * 8]);
            acc[mf] = __builtin_amdgcn_mfma_f32_16x16x32_bf16(ah, bh, acc[mf], 0, 0, 0);
            acc[mf] = __builtin_amdgcn_mfma_f32_16x16x32_bf16(ah, bl, acc[mf], 0, 0, 0);
            acc[mf] = __builtin_amdgcn_mfma_f32_16x16x32_bf16(al, bh, acc[mf], 0, 0, 0);
        }
    }
    float* db = dist + (size_t)bc * Nn * Nn;
#pragma unroll
    for (int mf = 0; mf < 4; ++mf) {
#pragma unroll
        for (int r = 0; r < 4; ++r) {
            const int rl = mf * 16 + lk * 4 + r;   // C/D: row=(l>>4)*4+r
            const float val = -acc[mf][r];
            Ds[rl][wv * 16 + lm] = val;            // col=lane&15
            const int rrow = r0 + rl;
            if (rrow < Nn && mcol < Nn)
                db[(size_t)rrow * Nn + mcol] = val;
        }
    }
    if (rt != mt) {
        __syncthreads();
        const int tx = tid & 15, ty = tid >> 4;
        const int rcol = r0 + tx * 4;              // full when rt<mt<=12
#pragma unroll
        for (int i = 0; i < 4; ++i) {
            const int mrow = m0 + ty * 4 + i;
            if (mrow < Nn) {
                float4 o = make_float4(Ds[tx*4+0][ty*4+i], Ds[tx*4+1][ty*4+i],
                                       Ds[tx*4+2][ty*4+i], Ds[tx*4+3][ty*4+i]);
                *reinterpret_cast<float4*>(&db[(size_t)mrow * Nn + rcol]) = o;
            }
        }
    }
}

// select16: one wave per row; 16x argmin-extract via shfl_xor; writes sorted
// candidate indices AND their fast dists. 8-batch chunks.
__global__ __launch_bounds__(256) void select16(
    const float* __restrict__ dist, int* __restrict__ cand,
    float* __restrict__ cdist, int bchunk)
{
    const int wid = blockIdx.x * 4 + (threadIdx.x >> 6);   // wave id in chunk
    const int L   = threadIdx.x & 63;
    const int r   = wid % Nn;
    const int bc  = wid / Nn;
    const int b   = bchunk * 8 + bc;
    const float* drow = dist + ((size_t)bc * Nn + r) * Nn;

    float v[13];
#pragma unroll
    for (int s = 0; s < 12; ++s) v[s] = drow[s * 64 + L];
    v[12] = (L < 16) ? drow[768 + L] : INFINITY;

    float mv = v[0]; int ms = 0;
#pragma unroll
    for (int s = 1; s < 13; ++s)
        if (v[s] < mv) { mv = v[s]; ms = s; }

    int out[16];
    float vals[16];
#pragma unroll
    for (int k = 0; k < 16; ++k) {
        float gv = mv; int gi = ms * 64 + L;
#pragma unroll
        for (int off = 1; off < 64; off <<= 1) {
            const float ov = __shfl_xor(gv, off, 64);
            const int   oi = __shfl_xor(gi, off, 64);
            if (ov < gv || (ov == gv && oi < gi)) { gv = ov; gi = oi; }
        }
        out[k] = gi; vals[k] = gv;
        const int ol = gi & 63, os = gi >> 6;
        if (L == ol) {
#pragma unroll
            for (int s = 0; s < 13; ++s) if (s == os) v[s] = INFINITY;
            mv = v[0]; ms = 0;
#pragma unroll
            for (int s = 1; s < 13; ++s)
                if (v[s] < mv) { mv = v[s]; ms = s; }
        }
    }
    if (L == 0) {
        int*   op = cand  + ((size_t)b * Nn + r) * 16;
        float* dp = cdist + ((size_t)b * Nn + r) * 16;
#pragma unroll
        for (int k = 0; k < 16; ++k) { op[k] = out[k]; dp[k] = vals[k]; }
    }
}

// zero_cnt: reset the ambiguous-row counter each launch (determinism).
__global__ void zero_cnt(int* cnt) { if (threadIdx.x == 0 && blockIdx.x == 0) *cnt = 0; }

// gap_route: clear-gap rows resolved directly from fast candidates; knife-edge
// rows appended to the ambiguous list.
__global__ __launch_bounds__(256) void gap_route(
    const int* __restrict__ cand, const float* __restrict__ cdist,
    int* __restrict__ nnidx, int* __restrict__ amb, int* __restrict__ cnt)
{
    const int idx = blockIdx.x * 256 + threadIdx.x;
    if (idx >= Bn * Nn) return;
    const float* dp = cdist + (size_t)idx * 16;
    const float d8 = dp[8], d9 = dp[9];
    if (d9 - d8 > GAP_DELTA) {
        const int* cp = cand + (size_t)idx * 16;
        int* op = nnidx + (size_t)idx * Kk;
#pragma unroll
        for (int k = 0; k < Kk; ++k) op[k] = cp[k];
    } else {
        const int pos = atomicAdd(cnt, 1);
        amb[pos] = idx;
    }
}

// refine_amb v3: one BLOCK per ambiguous row; reads the row-major xnT copy
// (contiguous 768B per vector). Group k computes candidate k's products into
// LDS; lane j==0 runs the BIT-EXACT sequential ascending-c add chain.
__global__ __launch_bounds__(256) void refine_amb(
    const float* __restrict__ xnT, const float* __restrict__ sq,
    const int* __restrict__ cand, const int* __restrict__ amb,
    const int* __restrict__ cnt, int* __restrict__ nnidx)
{
    __shared__ float prods[16][200];   // [cand][channel], padded
    __shared__ float Dd[16];
    __shared__ int   Dm[16];
    const int total = *cnt;
    const int k = threadIdx.x >> 4;    // candidate slot
    const int j = threadIdx.x & 15;    // channel segment

    for (int row = blockIdx.x; row < total; row += gridDim.x) {
        const int rowid = amb[row];
        const int b = rowid / Nn, r = rowid % Nn;
        const float* sqb = sq + (size_t)b * Nn;
        const int m = cand[(size_t)rowid * 16 + k];
        const float* rT = xnT + ((size_t)b * Nn + r) * Cc;
        const float* mT = xnT + ((size_t)b * Nn + m) * Cc;

#pragma unroll
        for (int i = 0; i < 12; ++i) {
            const int c = j * 12 + i;
            prods[k][c] = __fmul_rn(rT[c], mT[c]);
        }
        __syncthreads();
        if (j == 0) {
            float dot = 0.f;
            for (int c = 0; c < Cc; ++c)          // exact sequential chain
                dot = __fadd_rn(dot, prods[k][c]);
            const float t1 = __fmul_rn(2.f, dot);
            const float t2 = __fsub_rn(sqb[r], t1);
            Dd[k] = __fadd_rn(t2, sqb[m]);
            Dm[k] = m;
        }
        __syncthreads();
        if (threadIdx.x == 0) {
            float dl[16]; int il[16];
#pragma unroll
            for (int q = 0; q < 16; ++q) { dl[q] = Dd[q]; il[q] = Dm[q]; }
            int* op = nnidx + (size_t)rowid * Kk;
            for (int kk = 0; kk < Kk; ++kk) {
                int best = kk;
                for (int q = kk + 1; q < 16; ++q)
                    if (dl[q] < dl[best] || (dl[q] == dl[best] && il[q] < il[best])) best = q;
                float td = dl[kk]; dl[kk] = dl[best]; dl[best] = td;
                int ti = il[kk]; il[kk] = il[best]; il[best] = ti;
                op[kk] = il[kk];
            }
        }
        __syncthreads();
    }
}

// ===========================================================================
// VALUE PATH — bf16 MFMA (error budget 0.14; bf16 contributes ~0.03)
// ===========================================================================

// mr_pack v3: LDS-staged gather, packed bf16 transposed output (unchanged)
__global__ __launch_bounds__(256) void mr_pack(
    const float* __restrict__ xt, const int* __restrict__ nnidx,
    unsigned int* __restrict__ stT)
{
    __shared__ float rows[16][784];
    const int b   = blockIdx.y;
    const int c0  = blockIdx.x * 16;
    const int tid = threadIdx.x;
    const float* xb = xt + ((size_t)b * Cc + c0) * Nn;

#pragma unroll
    for (int c = 0; c < 16; ++c)
        for (int n = tid; n < Nn; n += 256)
            rows[c][n] = xb[(size_t)c * Nn + n];
    __syncthreads();

    for (int n = tid; n < Nn; n += 256) {
        const int* ip = nnidx + ((size_t)b * Nn + n) * Kk;
        int idx[Kk];
#pragma unroll
        for (int k = 0; k < Kk; ++k) idx[k] = ip[k];
        unsigned int pk[16];
#pragma unroll
        for (int c = 0; c < 16; ++c) {
            const float ctr = rows[c][n];
            float mx = -INFINITY;
#pragma unroll
            for (int k = 0; k < Kk; ++k)
                mx = fmaxf(mx, __fsub_rn(rows[c][idx[k]], ctr));
            pk[c] = (unsigned int)f2bf(ctr) | ((unsigned int)f2bf(mx) << 16);
        }
        unsigned int* dst = stT + ((size_t)b * Nn + n) * (C2c / 2) + c0;
#pragma unroll
        for (int q = 0; q < 4; ++q) {
            uint4 v = make_uint4(pk[q*4+0], pk[q*4+1], pk[q*4+2], pk[q*4+3]);
            *reinterpret_cast<uint4*>(&dst[q * 4]) = v;
        }
    }
}

__global__ __launch_bounds__(256) void wcvt(
    const float* __restrict__ w, unsigned short* __restrict__ wbf, int nElem)
{
    const int i = blockIdx.x * 256 + threadIdx.x;
    if (i < nElem) wbf[i] = f2bf(w[i]);
}

// gconv_mfma (unchanged)
__global__ __launch_bounds__(256) void gconv_mfma(
    const unsigned short* __restrict__ stT, const unsigned short* __restrict__ wbf2,
    const float* __restrict__ gb,
    const float* __restrict__ gg, const float* __restrict__ bb_,
    const float* __restrict__ mm, const float* __restrict__ vv,
    unsigned short* __restrict__ gT)
{
    const int b   = blockIdx.z;
    const int grp = blockIdx.y;
    const int n0  = blockIdx.x * 64;
    const int tid = threadIdx.x;
    const int wv  = tid >> 6;
    const int l   = tid & 63;
    const int lm  = l & 15, lk = l >> 4;

    const int ncol = n0 + wv * 16 + lm;
    const int ncl  = (ncol < Nn) ? ncol : (Nn - 1);
    const unsigned short* gRow = stT + ((size_t)b * Nn + ncl) * C2c + grp * 96;

    f32x4 acc[6];
#pragma unroll
    for (int mf = 0; mf < 6; ++mf) acc[mf] = (f32x4){0.f, 0.f, 0.f, 0.f};

#pragma unroll
    for (int k0 = 0; k0 < 96; k0 += 32) {
        bf16x8 bfr = *reinterpret_cast<const bf16x8*>(&gRow[k0 + lk * 8]);
#pragma unroll
        for (int mf = 0; mf < 6; ++mf) {
            bf16x8 afr = *reinterpret_cast<const bf16x8*>(
                &wbf2[((size_t)grp * 96 + mf * 16 + lm) * 96 + k0 + lk * 8]);
            acc[mf] = __builtin_amdgcn_mfma_f32_16x16x32_bf16(afr, bfr, acc[mf], 0, 0, 0);
        }
    }
    if (ncol < Nn) {
#pragma unroll
        for (int mf = 0; mf < 6; ++mf) {
            unsigned long long pk = 0ull;
#pragma unroll
            for (int r = 0; r < 4; ++r) {
                const int oc = grp * 96 + mf * 16 + lk * 4 + r;
                const float s  = gg[oc] * rsqrtf(vv[oc] + 1e-5f);
                const float sh = (gb[oc] - mm[oc]) * s + bb_[oc];
                float v = fmaf(acc[mf][r], s, sh);
                float ge = 0.5f * v * (1.f + erff(v * 0.70710678118654752f));
                pk |= ((unsigned long long)f2bf(ge)) << (16 * r);
            }
            *reinterpret_cast<unsigned long long*>(
                &gT[((size_t)b * Nn + ncol) * C2c + grp * 96 + mf * 16 + lk * 4]) = pk;
        }
    }
}

// fc2_mfma v3 (unchanged): LDS-staged weight k-slices
__global__ __launch_bounds__(256) void fc2_mfma(
    const unsigned short* __restrict__ gT, const unsigned short* __restrict__ wbf,
    const float* __restrict__ bias,
    const float* __restrict__ gg, const float* __restrict__ bb_,
    const float* __restrict__ mm, const float* __restrict__ vv,
    const float* __restrict__ xres,
    float* __restrict__ out)
{
    __shared__ float sS[192], sH[192];
    __shared__ unsigned short sW[192 * 40];
    const int b   = blockIdx.y;
    const int n0  = blockIdx.x * 64;
    const int tid = threadIdx.x;
    const int wv  = tid >> 6;
    const int l   = tid & 63;
    const int lm  = l & 15, lk = l >> 4;

    if (tid < 192) {
        const float s = gg[tid] * rsqrtf(vv[tid] + 1e-5f);
        sS[tid] = s;
        sH[tid] = (bias[tid] - mm[tid]) * s + bb_[tid];
    }

    const int ncol = n0 + wv * 16 + lm;
    const int ncl  = (ncol < Nn) ? ncol : (Nn - 1);
    const unsigned short* gRow = gT + ((size_t)b * Nn + ncl) * C2c;

    f32x4 acc[12];
#pragma unroll
    for (int mf = 0; mf < 12; ++mf) acc[mf] = (f32x4){0.f, 0.f, 0.f, 0.f};

    const int srow = tid >> 2, spart = tid & 3;
    for (int ks = 0; ks < 12; ++ks) {
        const int k0 = ks * 32;
        bf16x8 bfr = *reinterpret_cast<const bf16x8*>(&gRow[k0 + lk * 8]);
        __syncthreads();
#pragma unroll
        for (int p = 0; p < 3; ++p) {
            const int row = srow + p * 64;
            *reinterpret_cast<bf16x8*>(&sW[row * 40 + spart * 8]) =
                *reinterpret_cast<const bf16x8*>(&wbf[(size_t)row * C2c + k0 + spart * 8]);
        }
        __syncthreads();
#pragma unroll
        for (int mf = 0; mf < 12; ++mf) {
            bf16x8 afr = *reinterpret_cast<const bf16x8*>(&sW[(mf * 16 + lm) * 40 + lk * 8]);
            acc[mf] = __builtin_amdgcn_mfma_f32_16x16x32_bf16(afr, bfr, acc[mf], 0, 0, 0);
        }
    }
    if (ncol < Nn) {
#pragma unroll
        for (int mf = 0; mf < 12; ++mf) {
#pragma unroll
            for (int r = 0; r < 4; ++r) {
                const int o = mf * 16 + lk * 4 + r;   // C/D: row=(l>>4)*4+r
                const size_t oi = ((size_t)b * Cc + o) * Nn + ncol;  // col=lane&15
                out[oi] = fmaf(acc[mf][r], sS[o], sH[o]) + xres[oi];
            }
        }
    }
}

// ---------------------------------------------------------------------------
extern "C" void kernel_launch(void* const* d_in, const int* in_sizes, int n_in,
                              void* d_out, int out_size, void* d_ws, size_t ws_size,
                              hipStream_t stream)
{
    const float* x     = (const float*)d_in[0];
    const float* fc1_w = (const float*)d_in[1];
    const float* fc1_b = (const float*)d_in[2];
    const float* bn1_g = (const float*)d_in[3];
    const float* bn1_b = (const float*)d_in[4];
    const float* bn1_m = (const float*)d_in[5];
    const float* bn1_v = (const float*)d_in[6];
    const float* gc_w  = (const float*)d_in[7];
    const float* gc_b  = (const float*)d_in[8];
    const float* bn2_g = (const float*)d_in[9];
    const float* bn2_b = (const float*)d_in[10];
    const float* bn2_m = (const float*)d_in[11];
    const float* bn2_v = (const float*)d_in[12];
    const float* fc2_w = (const float*)d_in[13];
    const float* fc2_b = (const float*)d_in[14];
    const float* bn3_g = (const float*)d_in[15];
    const float* bn3_b = (const float*)d_in[16];
    const float* bn3_m = (const float*)d_in[17];
    const float* bn3_v = (const float*)d_in[18];

    float* out = (float*)d_out;                  // xt scratch, overwritten by fc2

    // workspace layout (max concurrent ~156 MB, proven):
    //   region A [0, 77.07M):
    //     dist8 [0, 19.67M) (8-batch chunks; dies after last select16)
    //     xnh  [19.67M, 38.94M) (dies after last dist_mfma)
    //     xnl  [38.94M, 58.20M) (dies after last dist_mfma)
    //     xnT  [0, 38.54M) born at xpose_f32 (over dead dist8+xnh); dies at refine
    //     stT  [0, 38.54M) born at mr_pack (over dead xnT)
    //   region B [77.07, 154.14M):
    //     xn | sq | c16 | cd16 (45.16M; die after refine/xpose)
    //     -> gT (bf16 38.5M, aliases xn, born at gconv)
    //     wbf (147KB) @ +45.16M | wbf2 (74KB) after it
    //   region C [154.14M, +): nnidx | amb | cnt
    char* wsb = (char*)d_ws;
    const size_t regionBytes = (size_t)Bn * C2c * Nn * 4;   // 77,070,336
    const size_t distBytes   = (size_t)8 * Nn * Nn * 4;     // 19,668,992
    const size_t bfBytes     = (size_t)Bn * Nn * Cc * 2;    // 19,267,584
    float* dist = (float*)wsb;
    unsigned short* xnh = (unsigned short*)(wsb + distBytes);
    unsigned short* xnl = (unsigned short*)(wsb + distBytes + bfBytes);
    float* xnT  = (float*)wsb;
    unsigned int*   stT32 = (unsigned int*)wsb;
    unsigned short* stT   = (unsigned short*)wsb;
    char*  g2   = wsb + regionBytes;
    float* xnb  = (float*)g2;                                      // 38,535,168 B
    float* sqb  = (float*)(g2 + (size_t)Bn * Cc * Nn * 4);         // 200,704 B
    int*   c16  = (int*)(g2 + (size_t)Bn * Cc * Nn * 4 + 200704);  // 3,211,264 B
    float* cd16 = (float*)(g2 + (size_t)Bn * Cc * Nn * 4 + 200704 + 3211264); // 3,211,264 B
    unsigned short* gT   = (unsigned short*)g2;                    // bf16, aliases xn
    unsigned short* wbf  = (unsigned short*)(g2 + 45158912);       // 147,456 B
    unsigned short* wbf2 = (unsigned short*)(g2 + 45158912 + 147456); // 73,728 B
    char*  g3   = wsb + 2 * regionBytes;
    int*   nni  = (int*)g3;                                        // 1,806,336 B
    int*   amb  = (int*)(g3 + 1806336);                            // 200,704 B
    int*   cnt  = (int*)(g3 + 1806336 + 200704);                   // 4 B

    const int nBN = Bn * Nn;

    dim3 blk(256);
    wcvt<<<dim3((Cc * C2c + 255) / 256), blk, 0, stream>>>(fc2_w, wbf, Cc * C2c);
    wcvt<<<dim3((4 * 96 * 96 + 255) / 256), blk, 0, stream>>>(gc_w, wbf2, 4 * 96 * 96);
    fc1_np<<<dim3(7, 3, Bn), blk, 0, stream>>>(
        x, fc1_w, fc1_b, bn1_g, bn1_b, bn1_m, bn1_v, out);
    norm_np<<<dim3((nBN + 255) / 256), blk, 0, stream>>>(out, xnb, sqb);
    xpose_bf<<<dim3(13, 3, Bn), blk, 0, stream>>>(xnb, xnh, xnl);
    for (int ch = 0; ch < 8; ++ch) {
        dist_mfma<<<dim3(91, 8), blk, 0, stream>>>(xnh, xnl, dist, ch);
        select16<<<dim3(8 * Nn / 4), blk, 0, stream>>>(dist, c16, cd16, ch);
    }
    xpose_f32<<<dim3(13, 3, Bn), blk, 0, stream>>>(xnb, xnT);
    zero_cnt<<<dim3(1), dim3(64), 0, stream>>>(cnt);
    gap_route<<<dim3((nBN + 255) / 256), blk, 0, stream>>>(c16, cd16, nni, amb, cnt);
    refine_amb<<<dim3(784), blk, 0, stream>>>(xnT, sqb, c16, amb, cnt, nni);
    mr_pack<<<dim3(12, Bn), blk, 0, stream>>>(out, nni, stT32);
    gconv_mfma<<<dim3(13, 4, Bn), blk, 0, stream>>>(
        stT, wbf2, gc_b, bn2_g, bn2_b, bn2_m, bn2_v, gT);
    fc2_mfma<<<dim3(13, Bn), blk, 0, stream>>>(
        gT, wbf, fc2_b, bn3_g, bn3_b, bn3_m, bn3_v, x, out);
}

// Round 20
// 601.570 us; speedup vs baseline: 1.1593x; 1.1593x over previous
//
#include <hip/hip_runtime.h>
#include <math.h>

static constexpr int Bn  = 64;    // batch
static constexpr int Cc  = 192;   // channels
static constexpr int Nn  = 784;   // H*W
static constexpr int C2c = 384;   // 2C
static constexpr int Kk  = 9;     // knn K
#define GAP_DELTA 1e-4f

typedef __attribute__((ext_vector_type(8))) short bf16x8;
typedef __attribute__((ext_vector_type(4))) float f32x4;

__device__ inline unsigned short f2bf(float f) {   // RNE f32 -> bf16
    unsigned int u = __float_as_uint(f);
    return (unsigned short)((u + 0x7FFFu + ((u >> 16) & 1u)) >> 16);
}

// ===========================================================================
// INDEX PATH — np-f32 bit-exact where values matter (fc1, norm, refine_amb).
// ===========================================================================

// fc1_np: BIT-CRITICAL — numpy-f32-exact (no FMA, ascending-c accumulation).
__global__ __launch_bounds__(256) void fc1_np(
    const float* __restrict__ x, const float* __restrict__ w,
    const float* __restrict__ bias,
    const float* __restrict__ gg, const float* __restrict__ bb_,
    const float* __restrict__ mm, const float* __restrict__ vv,
    float* __restrict__ xt)
{
    __shared__ float As[16][64];
    __shared__ float Bs[16][128];
    const int b   = blockIdx.z;
    const int n0  = blockIdx.x * 128;
    const int o0  = blockIdx.y * 64;
    const int tid = threadIdx.x;
    const int tx = tid & 15, ty = tid >> 4;
    const int lo = tid & 63, lk4 = tid >> 6;
    const int ln4 = tid & 15, lbk = tid >> 4;
    const float* xb = x + (size_t)b * Cc * Nn;

    float acc[4][8];
#pragma unroll
    for (int i = 0; i < 4; ++i)
#pragma unroll
        for (int j = 0; j < 8; ++j) acc[i][j] = 0.f;

    for (int kt = 0; kt < 12; ++kt) {               // c ascending: kt*16 + kk
        const int k0 = kt * 16;
        float4 av = *reinterpret_cast<const float4*>(&w[(size_t)(o0 + lo) * 192 + k0 + lk4 * 4]);
        As[lk4*4+0][lo] = av.x;
        As[lk4*4+1][lo] = av.y;
        As[lk4*4+2][lo] = av.z;
        As[lk4*4+3][lo] = av.w;
        const int na = n0 + ln4 * 4;
        const int nb = n0 + 64 + ln4 * 4;
        float4 b0 = make_float4(0.f, 0.f, 0.f, 0.f);
        float4 b1 = make_float4(0.f, 0.f, 0.f, 0.f);
        if (na < Nn) b0 = *reinterpret_cast<const float4*>(&xb[(size_t)(k0 + lbk) * Nn + na]);
        if (nb < Nn) b1 = *reinterpret_cast<const float4*>(&xb[(size_t)(k0 + lbk) * Nn + nb]);
        *reinterpret_cast<float4*>(&Bs[lbk][ln4*4])      = b0;
        *reinterpret_cast<float4*>(&Bs[lbk][64 + ln4*4]) = b1;
        __syncthreads();
#pragma unroll
        for (int kk = 0; kk < 16; ++kk) {
            float ar[4], br[8];
#pragma unroll
            for (int i = 0; i < 4; ++i) ar[i] = As[kk][ty*4+i];
#pragma unroll
            for (int j = 0; j < 4; ++j) br[j]     = Bs[kk][tx*4+j];
#pragma unroll
            for (int j = 0; j < 4; ++j) br[4 + j] = Bs[kk][64 + tx*4+j];
#pragma unroll
            for (int i = 0; i < 4; ++i)
#pragma unroll
                for (int j = 0; j < 8; ++j)
                    acc[i][j] = __fadd_rn(acc[i][j], __fmul_rn(ar[i], br[j]));
        }
        __syncthreads();
    }
    const int na = n0 + tx * 4;
    const int nb = n0 + 64 + tx * 4;
#pragma unroll
    for (int i = 0; i < 4; ++i) {
        const int o = o0 + ty * 4 + i;
        const float e  = __fadd_rn(vv[o], 1e-5f);
        const float r1 = __fsqrt_rn(e);
        const float rr = __fdiv_rn(1.f, r1);
        const float s  = __fmul_rn(gg[o], rr);
        const size_t rowb = ((size_t)b * Cc + o) * Nn;
        if (na < Nn) {
#pragma unroll
            for (int j = 0; j < 4; ++j) {
                const float h = __fadd_rn(acc[i][j], bias[o]);
                const float t = __fsub_rn(h, mm[o]);
                const float u = __fmul_rn(t, s);
                xt[rowb + na + j] = __fadd_rn(u, bb_[o]);
            }
        }
        if (nb < Nn) {
#pragma unroll
            for (int j = 0; j < 4; ++j) {
                const float h = __fadd_rn(acc[i][4 + j], bias[o]);
                const float t = __fsub_rn(h, mm[o]);
                const float u = __fmul_rn(t, s);
                xt[rowb + nb + j] = __fadd_rn(u, bb_[o]);
            }
        }
    }
}

// norm_np: numpy-exact. BIT-CRITICAL.
__global__ __launch_bounds__(256) void norm_np(
    const float* __restrict__ xt, float* __restrict__ xn, float* __restrict__ sq)
{
    const int idx = blockIdx.x * 256 + threadIdx.x;
    if (idx >= Bn * Nn) return;
    const int n = idx % Nn;
    const int b = idx / Nn;
    const float* p = xt + (size_t)b * Cc * Nn + n;

    float acc = 0.f;
    for (int c = 0; c < Cc; ++c) {
        const float v = p[(size_t)c * Nn];
        acc = __fadd_rn(acc, __fmul_rn(v, v));
    }
    float nrm = __fsqrt_rn(acc);
    nrm = fmaxf(nrm, 1e-12f);

    float* q = xn + (size_t)b * Cc * Nn + n;
    for (int c = 0; c < Cc; ++c)
        q[(size_t)c * Nn] = __fdiv_rn(p[(size_t)c * Nn], nrm);

    float sblk[2];
#pragma unroll
    for (int blk = 0; blk < 2; ++blk) {
        const int base = blk * 96;
        float r[8];
#pragma unroll
        for (int j = 0; j < 8; ++j) {
            const float xv = q[(size_t)(base + j) * Nn];
            r[j] = __fmul_rn(xv, xv);
        }
        for (int i = 8; i < 96; i += 8) {
#pragma unroll
            for (int j = 0; j < 8; ++j) {
                const float xv = q[(size_t)(base + i + j) * Nn];
                r[j] = __fadd_rn(r[j], __fmul_rn(xv, xv));
            }
        }
        sblk[blk] = __fadd_rn(__fadd_rn(__fadd_rn(r[0], r[1]), __fadd_rn(r[2], r[3])),
                              __fadd_rn(__fadd_rn(r[4], r[5]), __fadd_rn(r[6], r[7])));
    }
    sq[idx] = __fadd_rn(sblk[0], sblk[1]);
}

// xpose_bf: xn (col-major f32) -> split-bf16 row-major xnh/xnl[b][n][c].
__global__ __launch_bounds__(256) void xpose_bf(
    const float* __restrict__ xn, unsigned short* __restrict__ xnh,
    unsigned short* __restrict__ xnl)
{
    __shared__ float T[64][65];
    const int b  = blockIdx.z;
    const int c0 = blockIdx.y * 64;
    const int n0 = blockIdx.x * 64;
    const int tid = threadIdx.x;
    const int nl = tid & 63, cq = tid >> 6;

#pragma unroll
    for (int i = 0; i < 16; ++i) {
        const int c = c0 + cq + i * 4;
        const int n = n0 + nl;
        T[cq + i*4][nl] = (n < Nn) ? xn[((size_t)b * Cc + c) * Nn + n] : 0.f;
    }
    __syncthreads();
    const int nw = tid >> 2, cpart = tid & 3;
    const int n = n0 + nw;
    if (n < Nn) {
        unsigned short hbuf[16], lbuf[16];
#pragma unroll
        for (int j = 0; j < 16; ++j) {
            const float v = T[cpart * 16 + j][nw];
            const unsigned short h = f2bf(v);
            const float hf = __uint_as_float(((unsigned int)h) << 16);
            hbuf[j] = h;
            lbuf[j] = f2bf(__fsub_rn(v, hf));
        }
        unsigned short* dh = xnh + ((size_t)b * Nn + n) * Cc + c0 + cpart * 16;
        unsigned short* dl = xnl + ((size_t)b * Nn + n) * Cc + c0 + cpart * 16;
        *reinterpret_cast<bf16x8*>(&dh[0]) = *reinterpret_cast<bf16x8*>(&hbuf[0]);
        *reinterpret_cast<bf16x8*>(&dh[8]) = *reinterpret_cast<bf16x8*>(&hbuf[8]);
        *reinterpret_cast<bf16x8*>(&dl[0]) = *reinterpret_cast<bf16x8*>(&lbuf[0]);
        *reinterpret_cast<bf16x8*>(&dl[8]) = *reinterpret_cast<bf16x8*>(&lbuf[8]);
    }
}

// xpose_f32: xn (col-major) -> xnT[b][n][c] f32 row-major (bit-exact copy).
__global__ __launch_bounds__(256) void xpose_f32(
    const float* __restrict__ xn, float* __restrict__ xnT)
{
    __shared__ float T[64][65];
    const int b  = blockIdx.z;
    const int c0 = blockIdx.y * 64;
    const int n0 = blockIdx.x * 64;
    const int tid = threadIdx.x;
    const int nl = tid & 63, cq = tid >> 6;

#pragma unroll
    for (int i = 0; i < 16; ++i) {
        const int c = c0 + cq + i * 4;
        const int n = n0 + nl;
        T[cq + i*4][nl] = (n < Nn) ? xn[((size_t)b * Cc + c) * Nn + n] : 0.f;
    }
    __syncthreads();
    const int nw = tid >> 2, cpart = tid & 3;
    const int n = n0 + nw;
    if (n < Nn) {
        float* dst = xnT + ((size_t)b * Nn + n) * Cc + c0 + cpart * 16;
#pragma unroll
        for (int q = 0; q < 4; ++q) {
            float4 v = make_float4(T[cpart*16 + q*4 + 0][nw], T[cpart*16 + q*4 + 1][nw],
                                   T[cpart*16 + q*4 + 2][nw], T[cpart*16 + q*4 + 3][nw]);
            *reinterpret_cast<float4*>(&dst[q * 4]) = v;
        }
    }
}

// dist_mfma v2: split-bf16 MFMA filter with COOPERATIVE LDS STAGING of the
// A k-slice (Ah/Al[64][40], rows padded to 80B -> free 2-way ds_read_b128).
// B-fragments stay per-wave global loads (no cross-wave redundancy).
__global__ __launch_bounds__(256) void dist_mfma(
    const unsigned short* __restrict__ xnh, const unsigned short* __restrict__ xnl,
    float* __restrict__ dist, int bchunk)
{
    __shared__ float Ds[64][65];
    __shared__ unsigned short Ah[64 * 40];
    __shared__ unsigned short Al[64 * 40];
    const int bt = blockIdx.x;             // 0..90 (upper-triangle tiles)
    int rt = 0, rem = bt;
    while (rem >= 13 - rt) { rem -= 13 - rt; ++rt; }
    const int mt = rt + rem;
    const int bc = blockIdx.y;             // 0..7
    const int b  = bchunk * 8 + bc;
    const int r0 = rt * 64, m0 = mt * 64;
    const int tid = threadIdx.x;
    const int wv = tid >> 6, l = tid & 63;
    const int lm = l & 15, lk = l >> 4;

    const int mcol = m0 + wv * 16 + lm;
    const int mcl  = (mcol < Nn) ? mcol : (Nn - 1);
    const unsigned short* mh = xnh + ((size_t)b * Nn + mcl) * Cc;
    const unsigned short* ml = xnl + ((size_t)b * Nn + mcl) * Cc;

    const int srow = tid >> 2, spart = tid & 3;        // A staging task
    const int arow = r0 + srow;
    const int arowc = (arow < Nn) ? arow : (Nn - 1);
    const unsigned short* ah_src = xnh + ((size_t)b * Nn + arowc) * Cc;
    const unsigned short* al_src = xnl + ((size_t)b * Nn + arowc) * Cc;

    f32x4 acc[4];
#pragma unroll
    for (int mf = 0; mf < 4; ++mf) acc[mf] = (f32x4){0.f, 0.f, 0.f, 0.f};

#pragma unroll
    for (int ks = 0; ks < 6; ++ks) {
        const int k0 = ks * 32;
        bf16x8 bh = *reinterpret_cast<const bf16x8*>(&mh[k0 + lk * 8]);
        bf16x8 bl = *reinterpret_cast<const bf16x8*>(&ml[k0 + lk * 8]);
        __syncthreads();   // previous step's LDS reads complete
        *reinterpret_cast<bf16x8*>(&Ah[srow * 40 + spart * 8]) =
            *reinterpret_cast<const bf16x8*>(&ah_src[k0 + spart * 8]);
        *reinterpret_cast<bf16x8*>(&Al[srow * 40 + spart * 8]) =
            *reinterpret_cast<const bf16x8*>(&al_src[k0 + spart * 8]);
        __syncthreads();
#pragma unroll
        for (int mf = 0; mf < 4; ++mf) {
            bf16x8 ah = *reinterpret_cast<const bf16x8*>(&Ah[(mf * 16 + lm) * 40 + lk * 8]);
            bf16x8 al = *reinterpret_cast<const bf16x8*>(&Al[(mf * 16 + lm) * 40 + lk * 8]);
            acc[mf] = __builtin_amdgcn_mfma_f32_16x16x32_bf16(ah, bh, acc[mf], 0, 0, 0);
            acc[mf] = __builtin_amdgcn_mfma_f32_16x16x32_bf16(ah, bl, acc[mf], 0, 0, 0);
            acc[mf] = __builtin_amdgcn_mfma_f32_16x16x32_bf16(al, bh, acc[mf], 0, 0, 0);
        }
    }
    float* db = dist + (size_t)bc * Nn * Nn;
    __syncthreads();       // last step's Ah/Al reads done before Ds reuse... (separate arrays, but keep ordering cheap)
#pragma unroll
    for (int mf = 0; mf < 4; ++mf) {
#pragma unroll
        for (int r = 0; r < 4; ++r) {
            const int rl = mf * 16 + lk * 4 + r;   // C/D: row=(l>>4)*4+r
            const float val = -acc[mf][r];
            Ds[rl][wv * 16 + lm] = val;            // col=lane&15
            const int rrow = r0 + rl;
            if (rrow < Nn && mcol < Nn)
                db[(size_t)rrow * Nn + mcol] = val;
        }
    }
    if (rt != mt) {
        __syncthreads();
        const int tx = tid & 15, ty = tid >> 4;
        const int rcol = r0 + tx * 4;              // full when rt<mt<=12
#pragma unroll
        for (int i = 0; i < 4; ++i) {
            const int mrow = m0 + ty * 4 + i;
            if (mrow < Nn) {
                float4 o = make_float4(Ds[tx*4+0][ty*4+i], Ds[tx*4+1][ty*4+i],
                                       Ds[tx*4+2][ty*4+i], Ds[tx*4+3][ty*4+i]);
                *reinterpret_cast<float4*>(&db[(size_t)mrow * Nn + rcol]) = o;
            }
        }
    }
}

// select16: one wave per row; 16x argmin-extract via shfl_xor; writes sorted
// candidate indices AND their fast dists. 8-batch chunks.
__global__ __launch_bounds__(256) void select16(
    const float* __restrict__ dist, int* __restrict__ cand,
    float* __restrict__ cdist, int bchunk)
{
    const int wid = blockIdx.x * 4 + (threadIdx.x >> 6);   // wave id in chunk
    const int L   = threadIdx.x & 63;
    const int r   = wid % Nn;
    const int bc  = wid / Nn;
    const int b   = bchunk * 8 + bc;
    const float* drow = dist + ((size_t)bc * Nn + r) * Nn;

    float v[13];
#pragma unroll
    for (int s = 0; s < 12; ++s) v[s] = drow[s * 64 + L];
    v[12] = (L < 16) ? drow[768 + L] : INFINITY;

    float mv = v[0]; int ms = 0;
#pragma unroll
    for (int s = 1; s < 13; ++s)
        if (v[s] < mv) { mv = v[s]; ms = s; }

    int out[16];
    float vals[16];
#pragma unroll
    for (int k = 0; k < 16; ++k) {
        float gv = mv; int gi = ms * 64 + L;
#pragma unroll
        for (int off = 1; off < 64; off <<= 1) {
            const float ov = __shfl_xor(gv, off, 64);
            const int   oi = __shfl_xor(gi, off, 64);
            if (ov < gv || (ov == gv && oi < gi)) { gv = ov; gi = oi; }
        }
        out[k] = gi; vals[k] = gv;
        const int ol = gi & 63, os = gi >> 6;
        if (L == ol) {
#pragma unroll
            for (int s = 0; s < 13; ++s) if (s == os) v[s] = INFINITY;
            mv = v[0]; ms = 0;
#pragma unroll
            for (int s = 1; s < 13; ++s)
                if (v[s] < mv) { mv = v[s]; ms = s; }
        }
    }
    if (L == 0) {
        int*   op = cand  + ((size_t)b * Nn + r) * 16;
        float* dp = cdist + ((size_t)b * Nn + r) * 16;
#pragma unroll
        for (int k = 0; k < 16; ++k) { op[k] = out[k]; dp[k] = vals[k]; }
    }
}

// zero_cnt: reset the ambiguous-row counter each launch (determinism).
__global__ void zero_cnt(int* cnt) { if (threadIdx.x == 0 && blockIdx.x == 0) *cnt = 0; }

// gap_route: clear-gap rows resolved directly from fast candidates; knife-edge
// rows appended to the ambiguous list.
__global__ __launch_bounds__(256) void gap_route(
    const int* __restrict__ cand, const float* __restrict__ cdist,
    int* __restrict__ nnidx, int* __restrict__ amb, int* __restrict__ cnt)
{
    const int idx = blockIdx.x * 256 + threadIdx.x;
    if (idx >= Bn * Nn) return;
    const float* dp = cdist + (size_t)idx * 16;
    const float d8 = dp[8], d9 = dp[9];
    if (d9 - d8 > GAP_DELTA) {
        const int* cp = cand + (size_t)idx * 16;
        int* op = nnidx + (size_t)idx * Kk;
#pragma unroll
        for (int k = 0; k < Kk; ++k) op[k] = cp[k];
    } else {
        const int pos = atomicAdd(cnt, 1);
        amb[pos] = idx;
    }
}

// refine_amb v3: one BLOCK per ambiguous row; reads the row-major xnT copy.
// BIT-EXACT sequential ascending-c add chain.
__global__ __launch_bounds__(256) void refine_amb(
    const float* __restrict__ xnT, const float* __restrict__ sq,
    const int* __restrict__ cand, const int* __restrict__ amb,
    const int* __restrict__ cnt, int* __restrict__ nnidx)
{
    __shared__ float prods[16][200];   // [cand][channel], padded
    __shared__ float Dd[16];
    __shared__ int   Dm[16];
    const int total = *cnt;
    const int k = threadIdx.x >> 4;    // candidate slot
    const int j = threadIdx.x & 15;    // channel segment

    for (int row = blockIdx.x; row < total; row += gridDim.x) {
        const int rowid = amb[row];
        const int b = rowid / Nn, r = rowid % Nn;
        const float* sqb = sq + (size_t)b * Nn;
        const int m = cand[(size_t)rowid * 16 + k];
        const float* rT = xnT + ((size_t)b * Nn + r) * Cc;
        const float* mT = xnT + ((size_t)b * Nn + m) * Cc;

#pragma unroll
        for (int i = 0; i < 12; ++i) {
            const int c = j * 12 + i;
            prods[k][c] = __fmul_rn(rT[c], mT[c]);
        }
        __syncthreads();
        if (j == 0) {
            float dot = 0.f;
            for (int c = 0; c < Cc; ++c)          // exact sequential chain
                dot = __fadd_rn(dot, prods[k][c]);
            const float t1 = __fmul_rn(2.f, dot);
            const float t2 = __fsub_rn(sqb[r], t1);
            Dd[k] = __fadd_rn(t2, sqb[m]);
            Dm[k] = m;
        }
        __syncthreads();
        if (threadIdx.x == 0) {
            float dl[16]; int il[16];
#pragma unroll
            for (int q = 0; q < 16; ++q) { dl[q] = Dd[q]; il[q] = Dm[q]; }
            int* op = nnidx + (size_t)rowid * Kk;
            for (int kk = 0; kk < Kk; ++kk) {
                int best = kk;
                for (int q = kk + 1; q < 16; ++q)
                    if (dl[q] < dl[best] || (dl[q] == dl[best] && il[q] < il[best])) best = q;
                float td = dl[kk]; dl[kk] = dl[best]; dl[best] = td;
                int ti = il[kk]; il[kk] = il[best]; il[best] = ti;
                op[kk] = il[kk];
            }
        }
        __syncthreads();
    }
}

// ===========================================================================
// VALUE PATH — bf16 MFMA (error budget 0.14; bf16 contributes ~0.03)
// ===========================================================================

// mr_pack v3: LDS-staged gather, packed bf16 transposed output (unchanged)
__global__ __launch_bounds__(256) void mr_pack(
    const float* __restrict__ xt, const int* __restrict__ nnidx,
    unsigned int* __restrict__ stT)
{
    __shared__ float rows[16][784];
    const int b   = blockIdx.y;
    const int c0  = blockIdx.x * 16;
    const int tid = threadIdx.x;
    const float* xb = xt + ((size_t)b * Cc + c0) * Nn;

#pragma unroll
    for (int c = 0; c < 16; ++c)
        for (int n = tid; n < Nn; n += 256)
            rows[c][n] = xb[(size_t)c * Nn + n];
    __syncthreads();

    for (int n = tid; n < Nn; n += 256) {
        const int* ip = nnidx + ((size_t)b * Nn + n) * Kk;
        int idx[Kk];
#pragma unroll
        for (int k = 0; k < Kk; ++k) idx[k] = ip[k];
        unsigned int pk[16];
#pragma unroll
        for (int c = 0; c < 16; ++c) {
            const float ctr = rows[c][n];
            float mx = -INFINITY;
#pragma unroll
            for (int k = 0; k < Kk; ++k)
                mx = fmaxf(mx, __fsub_rn(rows[c][idx[k]], ctr));
            pk[c] = (unsigned int)f2bf(ctr) | ((unsigned int)f2bf(mx) << 16);
        }
        unsigned int* dst = stT + ((size_t)b * Nn + n) * (C2c / 2) + c0;
#pragma unroll
        for (int q = 0; q < 4; ++q) {
            uint4 v = make_uint4(pk[q*4+0], pk[q*4+1], pk[q*4+2], pk[q*4+3]);
            *reinterpret_cast<uint4*>(&dst[q * 4]) = v;
        }
    }
}

__global__ __launch_bounds__(256) void wcvt(
    const float* __restrict__ w, unsigned short* __restrict__ wbf, int nElem)
{
    const int i = blockIdx.x * 256 + threadIdx.x;
    if (i < nElem) wbf[i] = f2bf(w[i]);
}

// gconv_mfma (unchanged)
__global__ __launch_bounds__(256) void gconv_mfma(
    const unsigned short* __restrict__ stT, const unsigned short* __restrict__ wbf2,
    const float* __restrict__ gb,
    const float* __restrict__ gg, const float* __restrict__ bb_,
    const float* __restrict__ mm, const float* __restrict__ vv,
    unsigned short* __restrict__ gT)
{
    const int b   = blockIdx.z;
    const int grp = blockIdx.y;
    const int n0  = blockIdx.x * 64;
    const int tid = threadIdx.x;
    const int wv  = tid >> 6;
    const int l   = tid & 63;
    const int lm  = l & 15, lk = l >> 4;

    const int ncol = n0 + wv * 16 + lm;
    const int ncl  = (ncol < Nn) ? ncol : (Nn - 1);
    const unsigned short* gRow = stT + ((size_t)b * Nn + ncl) * C2c + grp * 96;

    f32x4 acc[6];
#pragma unroll
    for (int mf = 0; mf < 6; ++mf) acc[mf] = (f32x4){0.f, 0.f, 0.f, 0.f};

#pragma unroll
    for (int k0 = 0; k0 < 96; k0 += 32) {
        bf16x8 bfr = *reinterpret_cast<const bf16x8*>(&gRow[k0 + lk * 8]);
#pragma unroll
        for (int mf = 0; mf < 6; ++mf) {
            bf16x8 afr = *reinterpret_cast<const bf16x8*>(
                &wbf2[((size_t)grp * 96 + mf * 16 + lm) * 96 + k0 + lk * 8]);
            acc[mf] = __builtin_amdgcn_mfma_f32_16x16x32_bf16(afr, bfr, acc[mf], 0, 0, 0);
        }
    }
    if (ncol < Nn) {
#pragma unroll
        for (int mf = 0; mf < 6; ++mf) {
            unsigned long long pk = 0ull;
#pragma unroll
            for (int r = 0; r < 4; ++r) {
                const int oc = grp * 96 + mf * 16 + lk * 4 + r;
                const float s  = gg[oc] * rsqrtf(vv[oc] + 1e-5f);
                const float sh = (gb[oc] - mm[oc]) * s + bb_[oc];
                float v = fmaf(acc[mf][r], s, sh);
                float ge = 0.5f * v * (1.f + erff(v * 0.70710678118654752f));
                pk |= ((unsigned long long)f2bf(ge)) << (16 * r);
            }
            *reinterpret_cast<unsigned long long*>(
                &gT[((size_t)b * Nn + ncol) * C2c + grp * 96 + mf * 16 + lk * 4]) = pk;
        }
    }
}

// fc2_mfma v3 (unchanged): LDS-staged weight k-slices
__global__ __launch_bounds__(256) void fc2_mfma(
    const unsigned short* __restrict__ gT, const unsigned short* __restrict__ wbf,
    const float* __restrict__ bias,
    const float* __restrict__ gg, const float* __restrict__ bb_,
    const float* __restrict__ mm, const float* __restrict__ vv,
    const float* __restrict__ xres,
    float* __restrict__ out)
{
    __shared__ float sS[192], sH[192];
    __shared__ unsigned short sW[192 * 40];
    const int b   = blockIdx.y;
    const int n0  = blockIdx.x * 64;
    const int tid = threadIdx.x;
    const int wv  = tid >> 6;
    const int l   = tid & 63;
    const int lm  = l & 15, lk = l >> 4;

    if (tid < 192) {
        const float s = gg[tid] * rsqrtf(vv[tid] + 1e-5f);
        sS[tid] = s;
        sH[tid] = (bias[tid] - mm[tid]) * s + bb_[tid];
    }

    const int ncol = n0 + wv * 16 + lm;
    const int ncl  = (ncol < Nn) ? ncol : (Nn - 1);
    const unsigned short* gRow = gT + ((size_t)b * Nn + ncl) * C2c;

    f32x4 acc[12];
#pragma unroll
    for (int mf = 0; mf < 12; ++mf) acc[mf] = (f32x4){0.f, 0.f, 0.f, 0.f};

    const int srow = tid >> 2, spart = tid & 3;
    for (int ks = 0; ks < 12; ++ks) {
        const int k0 = ks * 32;
        bf16x8 bfr = *reinterpret_cast<const bf16x8*>(&gRow[k0 + lk * 8]);
        __syncthreads();
#pragma unroll
        for (int p = 0; p < 3; ++p) {
            const int row = srow + p * 64;
            *reinterpret_cast<bf16x8*>(&sW[row * 40 + spart * 8]) =
                *reinterpret_cast<const bf16x8*>(&wbf[(size_t)row * C2c + k0 + spart * 8]);
        }
        __syncthreads();
#pragma unroll
        for (int mf = 0; mf < 12; ++mf) {
            bf16x8 afr = *reinterpret_cast<const bf16x8*>(&sW[(mf * 16 + lm) * 40 + lk * 8]);
            acc[mf] = __builtin_amdgcn_mfma_f32_16x16x32_bf16(afr, bfr, acc[mf], 0, 0, 0);
        }
    }
    if (ncol < Nn) {
#pragma unroll
        for (int mf = 0; mf < 12; ++mf) {
#pragma unroll
            for (int r = 0; r < 4; ++r) {
                const int o = mf * 16 + lk * 4 + r;   // C/D: row=(l>>4)*4+r
                const size_t oi = ((size_t)b * Cc + o) * Nn + ncol;  // col=lane&15
                out[oi] = fmaf(acc[mf][r], sS[o], sH[o]) + xres[oi];
            }
        }
    }
}

// ---------------------------------------------------------------------------
extern "C" void kernel_launch(void* const* d_in, const int* in_sizes, int n_in,
                              void* d_out, int out_size, void* d_ws, size_t ws_size,
                              hipStream_t stream)
{
    const float* x     = (const float*)d_in[0];
    const float* fc1_w = (const float*)d_in[1];
    const float* fc1_b = (const float*)d_in[2];
    const float* bn1_g = (const float*)d_in[3];
    const float* bn1_b = (const float*)d_in[4];
    const float* bn1_m = (const float*)d_in[5];
    const float* bn1_v = (const float*)d_in[6];
    const float* gc_w  = (const float*)d_in[7];
    const float* gc_b  = (const float*)d_in[8];
    const float* bn2_g = (const float*)d_in[9];
    const float* bn2_b = (const float*)d_in[10];
    const float* bn2_m = (const float*)d_in[11];
    const float* bn2_v = (const float*)d_in[12];
    const float* fc2_w = (const float*)d_in[13];
    const float* fc2_b = (const float*)d_in[14];
    const float* bn3_g = (const float*)d_in[15];
    const float* bn3_b = (const float*)d_in[16];
    const float* bn3_m = (const float*)d_in[17];
    const float* bn3_v = (const float*)d_in[18];

    float* out = (float*)d_out;                  // xt scratch, overwritten by fc2

    // workspace layout (identical to round 19, proven):
    char* wsb = (char*)d_ws;
    const size_t regionBytes = (size_t)Bn * C2c * Nn * 4;   // 77,070,336
    const size_t distBytes   = (size_t)8 * Nn * Nn * 4;     // 19,668,992
    const size_t bfBytes     = (size_t)Bn * Nn * Cc * 2;    // 19,267,584
    float* dist = (float*)wsb;
    unsigned short* xnh = (unsigned short*)(wsb + distBytes);
    unsigned short* xnl = (unsigned short*)(wsb + distBytes + bfBytes);
    float* xnT  = (float*)wsb;
    unsigned int*   stT32 = (unsigned int*)wsb;
    unsigned short* stT   = (unsigned short*)wsb;
    char*  g2   = wsb + regionBytes;
    float* xnb  = (float*)g2;                                      // 38,535,168 B
    float* sqb  = (float*)(g2 + (size_t)Bn * Cc * Nn * 4);         // 200,704 B
    int*   c16  = (int*)(g2 + (size_t)Bn * Cc * Nn * 4 + 200704);  // 3,211,264 B
    float* cd16 = (float*)(g2 + (size_t)Bn * Cc * Nn * 4 + 200704 + 3211264); // 3,211,264 B
    unsigned short* gT   = (unsigned short*)g2;                    // bf16, aliases xn
    unsigned short* wbf  = (unsigned short*)(g2 + 45158912);       // 147,456 B
    unsigned short* wbf2 = (unsigned short*)(g2 + 45158912 + 147456); // 73,728 B
    char*  g3   = wsb + 2 * regionBytes;
    int*   nni  = (int*)g3;                                        // 1,806,336 B
    int*   amb  = (int*)(g3 + 1806336);                            // 200,704 B
    int*   cnt  = (int*)(g3 + 1806336 + 200704);                   // 4 B

    const int nBN = Bn * Nn;

    dim3 blk(256);
    wcvt<<<dim3((Cc * C2c + 255) / 256), blk, 0, stream>>>(fc2_w, wbf, Cc * C2c);
    wcvt<<<dim3((4 * 96 * 96 + 255) / 256), blk, 0, stream>>>(gc_w, wbf2, 4 * 96 * 96);
    fc1_np<<<dim3(7, 3, Bn), blk, 0, stream>>>(
        x, fc1_w, fc1_b, bn1_g, bn1_b, bn1_m, bn1_v, out);
    norm_np<<<dim3((nBN + 255) / 256), blk, 0, stream>>>(out, xnb, sqb);
    xpose_bf<<<dim3(13, 3, Bn), blk, 0, stream>>>(xnb, xnh, xnl);
    for (int ch = 0; ch < 8; ++ch) {
        dist_mfma<<<dim3(91, 8), blk, 0, stream>>>(xnh, xnl, dist, ch);
        select16<<<dim3(8 * Nn / 4), blk, 0, stream>>>(dist, c16, cd16, ch);
    }
    xpose_f32<<<dim3(13, 3, Bn), blk, 0, stream>>>(xnb, xnT);
    zero_cnt<<<dim3(1), dim3(64), 0, stream>>>(cnt);
    gap_route<<<dim3((nBN + 255) / 256), blk, 0, stream>>>(c16, cd16, nni, amb, cnt);
    refine_amb<<<dim3(784), blk, 0, stream>>>(xnT, sqb, c16, amb, cnt, nni);
    mr_pack<<<dim3(12, Bn), blk, 0, stream>>>(out, nni, stT32);
    gconv_mfma<<<dim3(13, 4, Bn), blk, 0, stream>>>(
        stT, wbf2, gc_b, bn2_g, bn2_b, bn2_m, bn2_v, gT);
    fc2_mfma<<<dim3(13, Bn), blk, 0, stream>>>(
        gT, wbf, fc2_b, bn3_g, bn3_b, bn3_m, bn3_v, x, out);
}

// Round 21
// 555.579 us; speedup vs baseline: 1.2552x; 1.0828x over previous
//
#include <hip/hip_runtime.h>
#include <math.h>

static constexpr int Bn  = 64;    // batch
static constexpr int Cc  = 192;   // channels
static constexpr int Nn  = 784;   // H*W
static constexpr int C2c = 384;   // 2C
static constexpr int Kk  = 9;     // knn K
#define GAP_DELTA 1e-4f

typedef __attribute__((ext_vector_type(8))) short bf16x8;
typedef __attribute__((ext_vector_type(4))) float f32x4;

__device__ inline unsigned short f2bf(float f) {   // RNE f32 -> bf16
    unsigned int u = __float_as_uint(f);
    return (unsigned short)((u + 0x7FFFu + ((u >> 16) & 1u)) >> 16);
}

// ===========================================================================
// INDEX PATH — np-f32 bit-exact where values matter (fc1, norm, refine_amb).
// ===========================================================================

// fc1_np v2: BIT-CRITICAL — numpy-f32-exact (no FMA, ascending-c accumulation).
// 96(o) x 128(n) tile, 6x8 per thread (higher op density than 4x8).
__global__ __launch_bounds__(256) void fc1_np(
    const float* __restrict__ x, const float* __restrict__ w,
    const float* __restrict__ bias,
    const float* __restrict__ gg, const float* __restrict__ bb_,
    const float* __restrict__ mm, const float* __restrict__ vv,
    float* __restrict__ xt)
{
    __shared__ float As[16][96];
    __shared__ float Bs[16][128];
    const int b   = blockIdx.z;
    const int n0  = blockIdx.x * 128;
    const int o0  = blockIdx.y * 96;
    const int tid = threadIdx.x;
    const int tx = tid & 15, ty = tid >> 4;
    const int ln4 = tid & 15, lbk = tid >> 4;
    const float* xb = x + (size_t)b * Cc * Nn;

    float acc[6][8];
#pragma unroll
    for (int i = 0; i < 6; ++i)
#pragma unroll
        for (int j = 0; j < 8; ++j) acc[i][j] = 0.f;

    for (int kt = 0; kt < 12; ++kt) {               // c ascending: kt*16 + kk
        const int k0 = kt * 16;
        // stage A: 96 rows x 16 k (384 float4 tasks over 256 threads)
        for (int t = tid; t < 384; t += 256) {
            const int row = t >> 2, part = t & 3;
            float4 av = *reinterpret_cast<const float4*>(
                &w[(size_t)(o0 + row) * 192 + k0 + part * 4]);
            As[part*4+0][row] = av.x;
            As[part*4+1][row] = av.y;
            As[part*4+2][row] = av.z;
            As[part*4+3][row] = av.w;
        }
        const int na = n0 + ln4 * 4;
        const int nb = n0 + 64 + ln4 * 4;
        float4 b0 = make_float4(0.f, 0.f, 0.f, 0.f);
        float4 b1 = make_float4(0.f, 0.f, 0.f, 0.f);
        if (na < Nn) b0 = *reinterpret_cast<const float4*>(&xb[(size_t)(k0 + lbk) * Nn + na]);
        if (nb < Nn) b1 = *reinterpret_cast<const float4*>(&xb[(size_t)(k0 + lbk) * Nn + nb]);
        *reinterpret_cast<float4*>(&Bs[lbk][ln4*4])      = b0;
        *reinterpret_cast<float4*>(&Bs[lbk][64 + ln4*4]) = b1;
        __syncthreads();
#pragma unroll
        for (int kk = 0; kk < 16; ++kk) {
            float ar[6], br[8];
#pragma unroll
            for (int i = 0; i < 6; ++i) ar[i] = As[kk][ty*6+i];
#pragma unroll
            for (int j = 0; j < 4; ++j) br[j]     = Bs[kk][tx*4+j];
#pragma unroll
            for (int j = 0; j < 4; ++j) br[4 + j] = Bs[kk][64 + tx*4+j];
#pragma unroll
            for (int i = 0; i < 6; ++i)
#pragma unroll
                for (int j = 0; j < 8; ++j)
                    acc[i][j] = __fadd_rn(acc[i][j], __fmul_rn(ar[i], br[j]));
        }
        __syncthreads();
    }
    const int na = n0 + tx * 4;
    const int nb = n0 + 64 + tx * 4;
#pragma unroll
    for (int i = 0; i < 6; ++i) {
        const int o = o0 + ty * 6 + i;
        const float e  = __fadd_rn(vv[o], 1e-5f);
        const float r1 = __fsqrt_rn(e);
        const float rr = __fdiv_rn(1.f, r1);
        const float s  = __fmul_rn(gg[o], rr);
        const size_t rowb = ((size_t)b * Cc + o) * Nn;
        if (na < Nn) {
#pragma unroll
            for (int j = 0; j < 4; ++j) {
                const float h = __fadd_rn(acc[i][j], bias[o]);
                const float t = __fsub_rn(h, mm[o]);
                const float u = __fmul_rn(t, s);
                xt[rowb + na + j] = __fadd_rn(u, bb_[o]);
            }
        }
        if (nb < Nn) {
#pragma unroll
            for (int j = 0; j < 4; ++j) {
                const float h = __fadd_rn(acc[i][4 + j], bias[o]);
                const float t = __fsub_rn(h, mm[o]);
                const float u = __fmul_rn(t, s);
                xt[rowb + nb + j] = __fadd_rn(u, bb_[o]);
            }
        }
    }
}

// norm_np: numpy-exact. BIT-CRITICAL.
__global__ __launch_bounds__(256) void norm_np(
    const float* __restrict__ xt, float* __restrict__ xn, float* __restrict__ sq)
{
    const int idx = blockIdx.x * 256 + threadIdx.x;
    if (idx >= Bn * Nn) return;
    const int n = idx % Nn;
    const int b = idx / Nn;
    const float* p = xt + (size_t)b * Cc * Nn + n;

    float acc = 0.f;
    for (int c = 0; c < Cc; ++c) {
        const float v = p[(size_t)c * Nn];
        acc = __fadd_rn(acc, __fmul_rn(v, v));
    }
    float nrm = __fsqrt_rn(acc);
    nrm = fmaxf(nrm, 1e-12f);

    float* q = xn + (size_t)b * Cc * Nn + n;
    for (int c = 0; c < Cc; ++c)
        q[(size_t)c * Nn] = __fdiv_rn(p[(size_t)c * Nn], nrm);

    float sblk[2];
#pragma unroll
    for (int blk = 0; blk < 2; ++blk) {
        const int base = blk * 96;
        float r[8];
#pragma unroll
        for (int j = 0; j < 8; ++j) {
            const float xv = q[(size_t)(base + j) * Nn];
            r[j] = __fmul_rn(xv, xv);
        }
        for (int i = 8; i < 96; i += 8) {
#pragma unroll
            for (int j = 0; j < 8; ++j) {
                const float xv = q[(size_t)(base + i + j) * Nn];
                r[j] = __fadd_rn(r[j], __fmul_rn(xv, xv));
            }
        }
        sblk[blk] = __fadd_rn(__fadd_rn(__fadd_rn(r[0], r[1]), __fadd_rn(r[2], r[3])),
                              __fadd_rn(__fadd_rn(r[4], r[5]), __fadd_rn(r[6], r[7])));
    }
    sq[idx] = __fadd_rn(sblk[0], sblk[1]);
}

// xpose_bf: xn (col-major f32) -> split-bf16 row-major xnh/xnl[b][n][c].
__global__ __launch_bounds__(256) void xpose_bf(
    const float* __restrict__ xn, unsigned short* __restrict__ xnh,
    unsigned short* __restrict__ xnl)
{
    __shared__ float T[64][65];
    const int b  = blockIdx.z;
    const int c0 = blockIdx.y * 64;
    const int n0 = blockIdx.x * 64;
    const int tid = threadIdx.x;
    const int nl = tid & 63, cq = tid >> 6;

#pragma unroll
    for (int i = 0; i < 16; ++i) {
        const int c = c0 + cq + i * 4;
        const int n = n0 + nl;
        T[cq + i*4][nl] = (n < Nn) ? xn[((size_t)b * Cc + c) * Nn + n] : 0.f;
    }
    __syncthreads();
    const int nw = tid >> 2, cpart = tid & 3;
    const int n = n0 + nw;
    if (n < Nn) {
        unsigned short hbuf[16], lbuf[16];
#pragma unroll
        for (int j = 0; j < 16; ++j) {
            const float v = T[cpart * 16 + j][nw];
            const unsigned short h = f2bf(v);
            const float hf = __uint_as_float(((unsigned int)h) << 16);
            hbuf[j] = h;
            lbuf[j] = f2bf(__fsub_rn(v, hf));
        }
        unsigned short* dh = xnh + ((size_t)b * Nn + n) * Cc + c0 + cpart * 16;
        unsigned short* dl = xnl + ((size_t)b * Nn + n) * Cc + c0 + cpart * 16;
        *reinterpret_cast<bf16x8*>(&dh[0]) = *reinterpret_cast<bf16x8*>(&hbuf[0]);
        *reinterpret_cast<bf16x8*>(&dh[8]) = *reinterpret_cast<bf16x8*>(&hbuf[8]);
        *reinterpret_cast<bf16x8*>(&dl[0]) = *reinterpret_cast<bf16x8*>(&lbuf[0]);
        *reinterpret_cast<bf16x8*>(&dl[8]) = *reinterpret_cast<bf16x8*>(&lbuf[8]);
    }
}

// xpose_f32: xn (col-major) -> xnT[b][n][c] f32 row-major (bit-exact copy).
__global__ __launch_bounds__(256) void xpose_f32(
    const float* __restrict__ xn, float* __restrict__ xnT)
{
    __shared__ float T[64][65];
    const int b  = blockIdx.z;
    const int c0 = blockIdx.y * 64;
    const int n0 = blockIdx.x * 64;
    const int tid = threadIdx.x;
    const int nl = tid & 63, cq = tid >> 6;

#pragma unroll
    for (int i = 0; i < 16; ++i) {
        const int c = c0 + cq + i * 4;
        const int n = n0 + nl;
        T[cq + i*4][nl] = (n < Nn) ? xn[((size_t)b * Cc + c) * Nn + n] : 0.f;
    }
    __syncthreads();
    const int nw = tid >> 2, cpart = tid & 3;
    const int n = n0 + nw;
    if (n < Nn) {
        float* dst = xnT + ((size_t)b * Nn + n) * Cc + c0 + cpart * 16;
#pragma unroll
        for (int q = 0; q < 4; ++q) {
            float4 v = make_float4(T[cpart*16 + q*4 + 0][nw], T[cpart*16 + q*4 + 1][nw],
                                   T[cpart*16 + q*4 + 2][nw], T[cpart*16 + q*4 + 3][nw]);
            *reinterpret_cast<float4*>(&dst[q * 4]) = v;
        }
    }
}

// dist_mfma v2: split-bf16 MFMA filter with cooperative LDS A staging.
__global__ __launch_bounds__(256) void dist_mfma(
    const unsigned short* __restrict__ xnh, const unsigned short* __restrict__ xnl,
    float* __restrict__ dist, int bchunk)
{
    __shared__ float Ds[64][65];
    __shared__ unsigned short Ah[64 * 40];
    __shared__ unsigned short Al[64 * 40];
    const int bt = blockIdx.x;             // 0..90 (upper-triangle tiles)
    int rt = 0, rem = bt;
    while (rem >= 13 - rt) { rem -= 13 - rt; ++rt; }
    const int mt = rt + rem;
    const int bc = blockIdx.y;             // 0..15
    const int b  = bchunk * 16 + bc;
    const int r0 = rt * 64, m0 = mt * 64;
    const int tid = threadIdx.x;
    const int wv = tid >> 6, l = tid & 63;
    const int lm = l & 15, lk = l >> 4;

    const int mcol = m0 + wv * 16 + lm;
    const int mcl  = (mcol < Nn) ? mcol : (Nn - 1);
    const unsigned short* mh = xnh + ((size_t)b * Nn + mcl) * Cc;
    const unsigned short* ml = xnl + ((size_t)b * Nn + mcl) * Cc;

    const int srow = tid >> 2, spart = tid & 3;        // A staging task
    const int arow = r0 + srow;
    const int arowc = (arow < Nn) ? arow : (Nn - 1);
    const unsigned short* ah_src = xnh + ((size_t)b * Nn + arowc) * Cc;
    const unsigned short* al_src = xnl + ((size_t)b * Nn + arowc) * Cc;

    f32x4 acc[4];
#pragma unroll
    for (int mf = 0; mf < 4; ++mf) acc[mf] = (f32x4){0.f, 0.f, 0.f, 0.f};

#pragma unroll
    for (int ks = 0; ks < 6; ++ks) {
        const int k0 = ks * 32;
        bf16x8 bh = *reinterpret_cast<const bf16x8*>(&mh[k0 + lk * 8]);
        bf16x8 bl = *reinterpret_cast<const bf16x8*>(&ml[k0 + lk * 8]);
        __syncthreads();   // previous step's LDS reads complete
        *reinterpret_cast<bf16x8*>(&Ah[srow * 40 + spart * 8]) =
            *reinterpret_cast<const bf16x8*>(&ah_src[k0 + spart * 8]);
        *reinterpret_cast<bf16x8*>(&Al[srow * 40 + spart * 8]) =
            *reinterpret_cast<const bf16x8*>(&al_src[k0 + spart * 8]);
        __syncthreads();
#pragma unroll
        for (int mf = 0; mf < 4; ++mf) {
            bf16x8 ah = *reinterpret_cast<const bf16x8*>(&Ah[(mf * 16 + lm) * 40 + lk * 8]);
            bf16x8 al = *reinterpret_cast<const bf16x8*>(&Al[(mf * 16 + lm) * 40 + lk * 8]);
            acc[mf] = __builtin_amdgcn_mfma_f32_16x16x32_bf16(ah, bh, acc[mf], 0, 0, 0);
            acc[mf] = __builtin_amdgcn_mfma_f32_16x16x32_bf16(ah, bl, acc[mf], 0, 0, 0);
            acc[mf] = __builtin_amdgcn_mfma_f32_16x16x32_bf16(al, bh, acc[mf], 0, 0, 0);
        }
    }
    float* db = dist + (size_t)bc * Nn * Nn;
    __syncthreads();
#pragma unroll
    for (int mf = 0; mf < 4; ++mf) {
#pragma unroll
        for (int r = 0; r < 4; ++r) {
            const int rl = mf * 16 + lk * 4 + r;   // C/D: row=(l>>4)*4+r
            const float val = -acc[mf][r];
            Ds[rl][wv * 16 + lm] = val;            // col=lane&15
            const int rrow = r0 + rl;
            if (rrow < Nn && mcol < Nn)
                db[(size_t)rrow * Nn + mcol] = val;
        }
    }
    if (rt != mt) {
        __syncthreads();
        const int tx = tid & 15, ty = tid >> 4;
        const int rcol = r0 + tx * 4;              // full when rt<mt<=12
#pragma unroll
        for (int i = 0; i < 4; ++i) {
            const int mrow = m0 + ty * 4 + i;
            if (mrow < Nn) {
                float4 o = make_float4(Ds[tx*4+0][ty*4+i], Ds[tx*4+1][ty*4+i],
                                       Ds[tx*4+2][ty*4+i], Ds[tx*4+3][ty*4+i]);
                *reinterpret_cast<float4*>(&db[(size_t)mrow * Nn + rcol]) = o;
            }
        }
    }
}

// select16: one wave per row; 16x argmin-extract via shfl_xor. 16-batch chunks.
__global__ __launch_bounds__(256) void select16(
    const float* __restrict__ dist, int* __restrict__ cand,
    float* __restrict__ cdist, int bchunk)
{
    const int wid = blockIdx.x * 4 + (threadIdx.x >> 6);   // wave id in chunk
    const int L   = threadIdx.x & 63;
    const int r   = wid % Nn;
    const int bc  = wid / Nn;
    const int b   = bchunk * 16 + bc;
    const float* drow = dist + ((size_t)bc * Nn + r) * Nn;

    float v[13];
#pragma unroll
    for (int s = 0; s < 12; ++s) v[s] = drow[s * 64 + L];
    v[12] = (L < 16) ? drow[768 + L] : INFINITY;

    float mv = v[0]; int ms = 0;
#pragma unroll
    for (int s = 1; s < 13; ++s)
        if (v[s] < mv) { mv = v[s]; ms = s; }

    int out[16];
    float vals[16];
#pragma unroll
    for (int k = 0; k < 16; ++k) {
        float gv = mv; int gi = ms * 64 + L;
#pragma unroll
        for (int off = 1; off < 64; off <<= 1) {
            const float ov = __shfl_xor(gv, off, 64);
            const int   oi = __shfl_xor(gi, off, 64);
            if (ov < gv || (ov == gv && oi < gi)) { gv = ov; gi = oi; }
        }
        out[k] = gi; vals[k] = gv;
        const int ol = gi & 63, os = gi >> 6;
        if (L == ol) {
#pragma unroll
            for (int s = 0; s < 13; ++s) if (s == os) v[s] = INFINITY;
            mv = v[0]; ms = 0;
#pragma unroll
            for (int s = 1; s < 13; ++s)
                if (v[s] < mv) { mv = v[s]; ms = s; }
        }
    }
    if (L == 0) {
        int*   op = cand  + ((size_t)b * Nn + r) * 16;
        float* dp = cdist + ((size_t)b * Nn + r) * 16;
#pragma unroll
        for (int k = 0; k < 16; ++k) { op[k] = out[k]; dp[k] = vals[k]; }
    }
}

// zero_cnt: reset the ambiguous-row counter each launch (determinism).
__global__ void zero_cnt(int* cnt) { if (threadIdx.x == 0 && blockIdx.x == 0) *cnt = 0; }

// gap_route: clear-gap rows resolved directly from fast candidates; knife-edge
// rows appended to the ambiguous list.
__global__ __launch_bounds__(256) void gap_route(
    const int* __restrict__ cand, const float* __restrict__ cdist,
    int* __restrict__ nnidx, int* __restrict__ amb, int* __restrict__ cnt)
{
    const int idx = blockIdx.x * 256 + threadIdx.x;
    if (idx >= Bn * Nn) return;
    const float* dp = cdist + (size_t)idx * 16;
    const float d8 = dp[8], d9 = dp[9];
    if (d9 - d8 > GAP_DELTA) {
        const int* cp = cand + (size_t)idx * 16;
        int* op = nnidx + (size_t)idx * Kk;
#pragma unroll
        for (int k = 0; k < Kk; ++k) op[k] = cp[k];
    } else {
        const int pos = atomicAdd(cnt, 1);
        amb[pos] = idx;
    }
}

// refine_amb v3: one BLOCK per ambiguous row; reads the row-major xnT copy.
// BIT-EXACT sequential ascending-c add chain.
__global__ __launch_bounds__(256) void refine_amb(
    const float* __restrict__ xnT, const float* __restrict__ sq,
    const int* __restrict__ cand, const int* __restrict__ amb,
    const int* __restrict__ cnt, int* __restrict__ nnidx)
{
    __shared__ float prods[16][200];   // [cand][channel], padded
    __shared__ float Dd[16];
    __shared__ int   Dm[16];
    const int total = *cnt;
    const int k = threadIdx.x >> 4;    // candidate slot
    const int j = threadIdx.x & 15;    // channel segment

    for (int row = blockIdx.x; row < total; row += gridDim.x) {
        const int rowid = amb[row];
        const int b = rowid / Nn, r = rowid % Nn;
        const float* sqb = sq + (size_t)b * Nn;
        const int m = cand[(size_t)rowid * 16 + k];
        const float* rT = xnT + ((size_t)b * Nn + r) * Cc;
        const float* mT = xnT + ((size_t)b * Nn + m) * Cc;

#pragma unroll
        for (int i = 0; i < 12; ++i) {
            const int c = j * 12 + i;
            prods[k][c] = __fmul_rn(rT[c], mT[c]);
        }
        __syncthreads();
        if (j == 0) {
            float dot = 0.f;
            for (int c = 0; c < Cc; ++c)          // exact sequential chain
                dot = __fadd_rn(dot, prods[k][c]);
            const float t1 = __fmul_rn(2.f, dot);
            const float t2 = __fsub_rn(sqb[r], t1);
            Dd[k] = __fadd_rn(t2, sqb[m]);
            Dm[k] = m;
        }
        __syncthreads();
        if (threadIdx.x == 0) {
            float dl[16]; int il[16];
#pragma unroll
            for (int q = 0; q < 16; ++q) { dl[q] = Dd[q]; il[q] = Dm[q]; }
            int* op = nnidx + (size_t)rowid * Kk;
            for (int kk = 0; kk < Kk; ++kk) {
                int best = kk;
                for (int q = kk + 1; q < 16; ++q)
                    if (dl[q] < dl[best] || (dl[q] == dl[best] && il[q] < il[best])) best = q;
                float td = dl[kk]; dl[kk] = dl[best]; dl[best] = td;
                int ti = il[kk]; il[kk] = il[best]; il[best] = ti;
                op[kk] = il[kk];
            }
        }
        __syncthreads();
    }
}

// ===========================================================================
// VALUE PATH — bf16 MFMA (error budget 0.14; bf16 contributes ~0.03)
// ===========================================================================

// mr_pack v3: LDS-staged gather, packed bf16 transposed output (unchanged)
__global__ __launch_bounds__(256) void mr_pack(
    const float* __restrict__ xt, const int* __restrict__ nnidx,
    unsigned int* __restrict__ stT)
{
    __shared__ float rows[16][784];
    const int b   = blockIdx.y;
    const int c0  = blockIdx.x * 16;
    const int tid = threadIdx.x;
    const float* xb = xt + ((size_t)b * Cc + c0) * Nn;

#pragma unroll
    for (int c = 0; c < 16; ++c)
        for (int n = tid; n < Nn; n += 256)
            rows[c][n] = xb[(size_t)c * Nn + n];
    __syncthreads();

    for (int n = tid; n < Nn; n += 256) {
        const int* ip = nnidx + ((size_t)b * Nn + n) * Kk;
        int idx[Kk];
#pragma unroll
        for (int k = 0; k < Kk; ++k) idx[k] = ip[k];
        unsigned int pk[16];
#pragma unroll
        for (int c = 0; c < 16; ++c) {
            const float ctr = rows[c][n];
            float mx = -INFINITY;
#pragma unroll
            for (int k = 0; k < Kk; ++k)
                mx = fmaxf(mx, __fsub_rn(rows[c][idx[k]], ctr));
            pk[c] = (unsigned int)f2bf(ctr) | ((unsigned int)f2bf(mx) << 16);
        }
        unsigned int* dst = stT + ((size_t)b * Nn + n) * (C2c / 2) + c0;
#pragma unroll
        for (int q = 0; q < 4; ++q) {
            uint4 v = make_uint4(pk[q*4+0], pk[q*4+1], pk[q*4+2], pk[q*4+3]);
            *reinterpret_cast<uint4*>(&dst[q * 4]) = v;
        }
    }
}

__global__ __launch_bounds__(256) void wcvt(
    const float* __restrict__ w, unsigned short* __restrict__ wbf, int nElem)
{
    const int i = blockIdx.x * 256 + threadIdx.x;
    if (i < nElem) wbf[i] = f2bf(w[i]);
}

// gconv_mfma (unchanged)
__global__ __launch_bounds__(256) void gconv_mfma(
    const unsigned short* __restrict__ stT, const unsigned short* __restrict__ wbf2,
    const float* __restrict__ gb,
    const float* __restrict__ gg, const float* __restrict__ bb_,
    const float* __restrict__ mm, const float* __restrict__ vv,
    unsigned short* __restrict__ gT)
{
    const int b   = blockIdx.z;
    const int grp = blockIdx.y;
    const int n0  = blockIdx.x * 64;
    const int tid = threadIdx.x;
    const int wv  = tid >> 6;
    const int l   = tid & 63;
    const int lm  = l & 15, lk = l >> 4;

    const int ncol = n0 + wv * 16 + lm;
    const int ncl  = (ncol < Nn) ? ncol : (Nn - 1);
    const unsigned short* gRow = stT + ((size_t)b * Nn + ncl) * C2c + grp * 96;

    f32x4 acc[6];
#pragma unroll
    for (int mf = 0; mf < 6; ++mf) acc[mf] = (f32x4){0.f, 0.f, 0.f, 0.f};

#pragma unroll
    for (int k0 = 0; k0 < 96; k0 += 32) {
        bf16x8 bfr = *reinterpret_cast<const bf16x8*>(&gRow[k0 + lk * 8]);
#pragma unroll
        for (int mf = 0; mf < 6; ++mf) {
            bf16x8 afr = *reinterpret_cast<const bf16x8*>(
                &wbf2[((size_t)grp * 96 + mf * 16 + lm) * 96 + k0 + lk * 8]);
            acc[mf] = __builtin_amdgcn_mfma_f32_16x16x32_bf16(afr, bfr, acc[mf], 0, 0, 0);
        }
    }
    if (ncol < Nn) {
#pragma unroll
        for (int mf = 0; mf < 6; ++mf) {
            unsigned long long pk = 0ull;
#pragma unroll
            for (int r = 0; r < 4; ++r) {
                const int oc = grp * 96 + mf * 16 + lk * 4 + r;
                const float s  = gg[oc] * rsqrtf(vv[oc] + 1e-5f);
                const float sh = (gb[oc] - mm[oc]) * s + bb_[oc];
                float v = fmaf(acc[mf][r], s, sh);
                float ge = 0.5f * v * (1.f + erff(v * 0.70710678118654752f));
                pk |= ((unsigned long long)f2bf(ge)) << (16 * r);
            }
            *reinterpret_cast<unsigned long long*>(
                &gT[((size_t)b * Nn + ncol) * C2c + grp * 96 + mf * 16 + lk * 4]) = pk;
        }
    }
}

// fc2_mfma v3 (unchanged): LDS-staged weight k-slices
__global__ __launch_bounds__(256) void fc2_mfma(
    const unsigned short* __restrict__ gT, const unsigned short* __restrict__ wbf,
    const float* __restrict__ bias,
    const float* __restrict__ gg, const float* __restrict__ bb_,
    const float* __restrict__ mm, const float* __restrict__ vv,
    const float* __restrict__ xres,
    float* __restrict__ out)
{
    __shared__ float sS[192], sH[192];
    __shared__ unsigned short sW[192 * 40];
    const int b   = blockIdx.y;
    const int n0  = blockIdx.x * 64;
    const int tid = threadIdx.x;
    const int wv  = tid >> 6;
    const int l   = tid & 63;
    const int lm  = l & 15, lk = l >> 4;

    if (tid < 192) {
        const float s = gg[tid] * rsqrtf(vv[tid] + 1e-5f);
        sS[tid] = s;
        sH[tid] = (bias[tid] - mm[tid]) * s + bb_[tid];
    }

    const int ncol = n0 + wv * 16 + lm;
    const int ncl  = (ncol < Nn) ? ncol : (Nn - 1);
    const unsigned short* gRow = gT + ((size_t)b * Nn + ncl) * C2c;

    f32x4 acc[12];
#pragma unroll
    for (int mf = 0; mf < 12; ++mf) acc[mf] = (f32x4){0.f, 0.f, 0.f, 0.f};

    const int srow = tid >> 2, spart = tid & 3;
    for (int ks = 0; ks < 12; ++ks) {
        const int k0 = ks * 32;
        bf16x8 bfr = *reinterpret_cast<const bf16x8*>(&gRow[k0 + lk * 8]);
        __syncthreads();
#pragma unroll
        for (int p = 0; p < 3; ++p) {
            const int row = srow + p * 64;
            *reinterpret_cast<bf16x8*>(&sW[row * 40 + spart * 8]) =
                *reinterpret_cast<const bf16x8*>(&wbf[(size_t)row * C2c + k0 + spart * 8]);
        }
        __syncthreads();
#pragma unroll
        for (int mf = 0; mf < 12; ++mf) {
            bf16x8 afr = *reinterpret_cast<const bf16x8*>(&sW[(mf * 16 + lm) * 40 + lk * 8]);
            acc[mf] = __builtin_amdgcn_mfma_f32_16x16x32_bf16(afr, bfr, acc[mf], 0, 0, 0);
        }
    }
    if (ncol < Nn) {
#pragma unroll
        for (int mf = 0; mf < 12; ++mf) {
#pragma unroll
            for (int r = 0; r < 4; ++r) {
                const int o = mf * 16 + lk * 4 + r;   // C/D: row=(l>>4)*4+r
                const size_t oi = ((size_t)b * Cc + o) * Nn + ncol;  // col=lane&15
                out[oi] = fmaf(acc[mf][r], sS[o], sH[o]) + xres[oi];
            }
        }
    }
}

// ---------------------------------------------------------------------------
extern "C" void kernel_launch(void* const* d_in, const int* in_sizes, int n_in,
                              void* d_out, int out_size, void* d_ws, size_t ws_size,
                              hipStream_t stream)
{
    const float* x     = (const float*)d_in[0];
    const float* fc1_w = (const float*)d_in[1];
    const float* fc1_b = (const float*)d_in[2];
    const float* bn1_g = (const float*)d_in[3];
    const float* bn1_b = (const float*)d_in[4];
    const float* bn1_m = (const float*)d_in[5];
    const float* bn1_v = (const float*)d_in[6];
    const float* gc_w  = (const float*)d_in[7];
    const float* gc_b  = (const float*)d_in[8];
    const float* bn2_g = (const float*)d_in[9];
    const float* bn2_b = (const float*)d_in[10];
    const float* bn2_m = (const float*)d_in[11];
    const float* bn2_v = (const float*)d_in[12];
    const float* fc2_w = (const float*)d_in[13];
    const float* fc2_b = (const float*)d_in[14];
    const float* bn3_g = (const float*)d_in[15];
    const float* bn3_b = (const float*)d_in[16];
    const float* bn3_m = (const float*)d_in[17];
    const float* bn3_v = (const float*)d_in[18];

    float* out = (float*)d_out;                  // xt scratch, overwritten by fc2

    // workspace layout (max concurrent ~156 MB):
    //   region A [0, 77.07M):
    //     dist16 [0, 39.34M) (16-batch chunks; dies after last select16)
    //     xnh   [39.34M, 58.61M) (dies after last dist_mfma)
    //     xnT   [0, 38.54M) born at xpose_f32 (over dead dist16); dies at refine
    //     stT   [0, 38.54M) born at mr_pack (over dead xnT)
    //   region B [77.07, 154.14M):
    //     xn | sq | c16 | cd16 (45.16M; die after refine/xpose)
    //     wbf (147KB) @ +45.16M | wbf2 (74KB)
    //     xnl @ +45.38M (19.27M; dies after last dist_mfma)
    //     -> gT (bf16 38.5M, aliases xn, born at gconv)
    //   region C [154.14M, +): nnidx | amb | cnt
    char* wsb = (char*)d_ws;
    const size_t regionBytes = (size_t)Bn * C2c * Nn * 4;    // 77,070,336
    const size_t distBytes   = (size_t)16 * Nn * Nn * 4;     // 39,337,984
    float* dist = (float*)wsb;
    unsigned short* xnh = (unsigned short*)(wsb + distBytes);
    float* xnT  = (float*)wsb;
    unsigned int*   stT32 = (unsigned int*)wsb;
    unsigned short* stT   = (unsigned short*)wsb;
    char*  g2   = wsb + regionBytes;
    float* xnb  = (float*)g2;                                      // 38,535,168 B
    float* sqb  = (float*)(g2 + (size_t)Bn * Cc * Nn * 4);         // 200,704 B
    int*   c16  = (int*)(g2 + (size_t)Bn * Cc * Nn * 4 + 200704);  // 3,211,264 B
    float* cd16 = (float*)(g2 + (size_t)Bn * Cc * Nn * 4 + 200704 + 3211264); // 3,211,264 B
    unsigned short* gT   = (unsigned short*)g2;                    // bf16, aliases xn
    unsigned short* wbf  = (unsigned short*)(g2 + 45158912);       // 147,456 B
    unsigned short* wbf2 = (unsigned short*)(g2 + 45158912 + 147456); // 73,728 B
    unsigned short* xnl  = (unsigned short*)(g2 + 45158912 + 147456 + 73728); // 19,267,584 B
    char*  g3   = wsb + 2 * regionBytes;
    int*   nni  = (int*)g3;                                        // 1,806,336 B
    int*   amb  = (int*)(g3 + 1806336);                            // 200,704 B
    int*   cnt  = (int*)(g3 + 1806336 + 200704);                   // 4 B

    const int nBN = Bn * Nn;

    dim3 blk(256);
    wcvt<<<dim3((Cc * C2c + 255) / 256), blk, 0, stream>>>(fc2_w, wbf, Cc * C2c);
    wcvt<<<dim3((4 * 96 * 96 + 255) / 256), blk, 0, stream>>>(gc_w, wbf2, 4 * 96 * 96);
    fc1_np<<<dim3(7, 2, Bn), blk, 0, stream>>>(
        x, fc1_w, fc1_b, bn1_g, bn1_b, bn1_m, bn1_v, out);
    norm_np<<<dim3((nBN + 255) / 256), blk, 0, stream>>>(out, xnb, sqb);
    xpose_bf<<<dim3(13, 3, Bn), blk, 0, stream>>>(xnb, xnh, xnl);
    for (int ch = 0; ch < 4; ++ch) {
        dist_mfma<<<dim3(91, 16), blk, 0, stream>>>(xnh, xnl, dist, ch);
        select16<<<dim3(16 * Nn / 4), blk, 0, stream>>>(dist, c16, cd16, ch);
    }
    xpose_f32<<<dim3(13, 3, Bn), blk, 0, stream>>>(xnb, xnT);
    zero_cnt<<<dim3(1), dim3(64), 0, stream>>>(cnt);
    gap_route<<<dim3((nBN + 255) / 256), blk, 0, stream>>>(c16, cd16, nni, amb, cnt);
    refine_amb<<<dim3(784), blk, 0, stream>>>(xnT, sqb, c16, amb, cnt, nni);
    mr_pack<<<dim3(12, Bn), blk, 0, stream>>>(out, nni, stT32);
    gconv_mfma<<<dim3(13, 4, Bn), blk, 0, stream>>>(
        stT, wbf2, gc_b, bn2_g, bn2_b, bn2_m, bn2_v, gT);
    fc2_mfma<<<dim3(13, Bn), blk, 0, stream>>>(
        gT, wbf, fc2_b, bn3_g, bn3_b, bn3_m, bn3_v, x, out);
}

// Round 22
// 550.798 us; speedup vs baseline: 1.2661x; 1.0087x over previous
//
#include <hip/hip_runtime.h>
#include <math.h>

static constexpr int Bn  = 64;    // batch
static constexpr int Cc  = 192;   // channels
static constexpr int Nn  = 784;   // H*W
static constexpr int C2c = 384;   // 2C
static constexpr int Kk  = 9;     // knn K
#define GAP_DELTA 1e-4f

typedef __attribute__((ext_vector_type(8))) short bf16x8;
typedef __attribute__((ext_vector_type(4))) float f32x4;

__device__ inline unsigned short f2bf(float f) {   // RNE f32 -> bf16
    unsigned int u = __float_as_uint(f);
    return (unsigned short)((u + 0x7FFFu + ((u >> 16) & 1u)) >> 16);
}

// ===========================================================================
// INDEX PATH — np-f32 bit-exact where values matter (fc1, norm, refine_amb).
// ===========================================================================

// fc1_np: BIT-CRITICAL — numpy-f32-exact (no FMA, ascending-c accumulation).
// 64(o) x 128(n) tile, 4x8 per thread (proven conflict-free pattern).
__global__ __launch_bounds__(256) void fc1_np(
    const float* __restrict__ x, const float* __restrict__ w,
    const float* __restrict__ bias,
    const float* __restrict__ gg, const float* __restrict__ bb_,
    const float* __restrict__ mm, const float* __restrict__ vv,
    float* __restrict__ xt)
{
    __shared__ float As[16][64];
    __shared__ float Bs[16][128];
    const int b   = blockIdx.z;
    const int n0  = blockIdx.x * 128;
    const int o0  = blockIdx.y * 64;
    const int tid = threadIdx.x;
    const int tx = tid & 15, ty = tid >> 4;
    const int lo = tid & 63, lk4 = tid >> 6;
    const int ln4 = tid & 15, lbk = tid >> 4;
    const float* xb = x + (size_t)b * Cc * Nn;

    float acc[4][8];
#pragma unroll
    for (int i = 0; i < 4; ++i)
#pragma unroll
        for (int j = 0; j < 8; ++j) acc[i][j] = 0.f;

    for (int kt = 0; kt < 12; ++kt) {               // c ascending: kt*16 + kk
        const int k0 = kt * 16;
        float4 av = *reinterpret_cast<const float4*>(&w[(size_t)(o0 + lo) * 192 + k0 + lk4 * 4]);
        As[lk4*4+0][lo] = av.x;
        As[lk4*4+1][lo] = av.y;
        As[lk4*4+2][lo] = av.z;
        As[lk4*4+3][lo] = av.w;
        const int na = n0 + ln4 * 4;
        const int nb = n0 + 64 + ln4 * 4;
        float4 b0 = make_float4(0.f, 0.f, 0.f, 0.f);
        float4 b1 = make_float4(0.f, 0.f, 0.f, 0.f);
        if (na < Nn) b0 = *reinterpret_cast<const float4*>(&xb[(size_t)(k0 + lbk) * Nn + na]);
        if (nb < Nn) b1 = *reinterpret_cast<const float4*>(&xb[(size_t)(k0 + lbk) * Nn + nb]);
        *reinterpret_cast<float4*>(&Bs[lbk][ln4*4])      = b0;
        *reinterpret_cast<float4*>(&Bs[lbk][64 + ln4*4]) = b1;
        __syncthreads();
#pragma unroll
        for (int kk = 0; kk < 16; ++kk) {
            float ar[4], br[8];
#pragma unroll
            for (int i = 0; i < 4; ++i) ar[i] = As[kk][ty*4+i];
#pragma unroll
            for (int j = 0; j < 4; ++j) br[j]     = Bs[kk][tx*4+j];
#pragma unroll
            for (int j = 0; j < 4; ++j) br[4 + j] = Bs[kk][64 + tx*4+j];
#pragma unroll
            for (int i = 0; i < 4; ++i)
#pragma unroll
                for (int j = 0; j < 8; ++j)
                    acc[i][j] = __fadd_rn(acc[i][j], __fmul_rn(ar[i], br[j]));
        }
        __syncthreads();
    }
    const int na = n0 + tx * 4;
    const int nb = n0 + 64 + tx * 4;
#pragma unroll
    for (int i = 0; i < 4; ++i) {
        const int o = o0 + ty * 4 + i;
        const float e  = __fadd_rn(vv[o], 1e-5f);
        const float r1 = __fsqrt_rn(e);
        const float rr = __fdiv_rn(1.f, r1);
        const float s  = __fmul_rn(gg[o], rr);
        const size_t rowb = ((size_t)b * Cc + o) * Nn;
        if (na < Nn) {
#pragma unroll
            for (int j = 0; j < 4; ++j) {
                const float h = __fadd_rn(acc[i][j], bias[o]);
                const float t = __fsub_rn(h, mm[o]);
                const float u = __fmul_rn(t, s);
                xt[rowb + na + j] = __fadd_rn(u, bb_[o]);
            }
        }
        if (nb < Nn) {
#pragma unroll
            for (int j = 0; j < 4; ++j) {
                const float h = __fadd_rn(acc[i][4 + j], bias[o]);
                const float t = __fsub_rn(h, mm[o]);
                const float u = __fmul_rn(t, s);
                xt[rowb + nb + j] = __fadd_rn(u, bb_[o]);
            }
        }
    }
}

// norm_np: numpy-exact. BIT-CRITICAL.
__global__ __launch_bounds__(256) void norm_np(
    const float* __restrict__ xt, float* __restrict__ xn, float* __restrict__ sq)
{
    const int idx = blockIdx.x * 256 + threadIdx.x;
    if (idx >= Bn * Nn) return;
    const int n = idx % Nn;
    const int b = idx / Nn;
    const float* p = xt + (size_t)b * Cc * Nn + n;

    float acc = 0.f;
    for (int c = 0; c < Cc; ++c) {
        const float v = p[(size_t)c * Nn];
        acc = __fadd_rn(acc, __fmul_rn(v, v));
    }
    float nrm = __fsqrt_rn(acc);
    nrm = fmaxf(nrm, 1e-12f);

    float* q = xn + (size_t)b * Cc * Nn + n;
    for (int c = 0; c < Cc; ++c)
        q[(size_t)c * Nn] = __fdiv_rn(p[(size_t)c * Nn], nrm);

    float sblk[2];
#pragma unroll
    for (int blk = 0; blk < 2; ++blk) {
        const int base = blk * 96;
        float r[8];
#pragma unroll
        for (int j = 0; j < 8; ++j) {
            const float xv = q[(size_t)(base + j) * Nn];
            r[j] = __fmul_rn(xv, xv);
        }
        for (int i = 8; i < 96; i += 8) {
#pragma unroll
            for (int j = 0; j < 8; ++j) {
                const float xv = q[(size_t)(base + i + j) * Nn];
                r[j] = __fadd_rn(r[j], __fmul_rn(xv, xv));
            }
        }
        sblk[blk] = __fadd_rn(__fadd_rn(__fadd_rn(r[0], r[1]), __fadd_rn(r[2], r[3])),
                              __fadd_rn(__fadd_rn(r[4], r[5]), __fadd_rn(r[6], r[7])));
    }
    sq[idx] = __fadd_rn(sblk[0], sblk[1]);
}

// xpose_bf: xn (col-major f32) -> split-bf16 row-major xnh/xnl[b][n][c].
__global__ __launch_bounds__(256) void xpose_bf(
    const float* __restrict__ xn, unsigned short* __restrict__ xnh,
    unsigned short* __restrict__ xnl)
{
    __shared__ float T[64][65];
    const int b  = blockIdx.z;
    const int c0 = blockIdx.y * 64;
    const int n0 = blockIdx.x * 64;
    const int tid = threadIdx.x;
    const int nl = tid & 63, cq = tid >> 6;

#pragma unroll
    for (int i = 0; i < 16; ++i) {
        const int c = c0 + cq + i * 4;
        const int n = n0 + nl;
        T[cq + i*4][nl] = (n < Nn) ? xn[((size_t)b * Cc + c) * Nn + n] : 0.f;
    }
    __syncthreads();
    const int nw = tid >> 2, cpart = tid & 3;
    const int n = n0 + nw;
    if (n < Nn) {
        unsigned short hbuf[16], lbuf[16];
#pragma unroll
        for (int j = 0; j < 16; ++j) {
            const float v = T[cpart * 16 + j][nw];
            const unsigned short h = f2bf(v);
            const float hf = __uint_as_float(((unsigned int)h) << 16);
            hbuf[j] = h;
            lbuf[j] = f2bf(__fsub_rn(v, hf));
        }
        unsigned short* dh = xnh + ((size_t)b * Nn + n) * Cc + c0 + cpart * 16;
        unsigned short* dl = xnl + ((size_t)b * Nn + n) * Cc + c0 + cpart * 16;
        *reinterpret_cast<bf16x8*>(&dh[0]) = *reinterpret_cast<bf16x8*>(&hbuf[0]);
        *reinterpret_cast<bf16x8*>(&dh[8]) = *reinterpret_cast<bf16x8*>(&hbuf[8]);
        *reinterpret_cast<bf16x8*>(&dl[0]) = *reinterpret_cast<bf16x8*>(&lbuf[0]);
        *reinterpret_cast<bf16x8*>(&dl[8]) = *reinterpret_cast<bf16x8*>(&lbuf[8]);
    }
}

// xpose_f32: xn (col-major) -> xnT[b][n][c] f32 row-major (bit-exact copy).
__global__ __launch_bounds__(256) void xpose_f32(
    const float* __restrict__ xn, float* __restrict__ xnT)
{
    __shared__ float T[64][65];
    const int b  = blockIdx.z;
    const int c0 = blockIdx.y * 64;
    const int n0 = blockIdx.x * 64;
    const int tid = threadIdx.x;
    const int nl = tid & 63, cq = tid >> 6;

#pragma unroll
    for (int i = 0; i < 16; ++i) {
        const int c = c0 + cq + i * 4;
        const int n = n0 + nl;
        T[cq + i*4][nl] = (n < Nn) ? xn[((size_t)b * Cc + c) * Nn + n] : 0.f;
    }
    __syncthreads();
    const int nw = tid >> 2, cpart = tid & 3;
    const int n = n0 + nw;
    if (n < Nn) {
        float* dst = xnT + ((size_t)b * Nn + n) * Cc + c0 + cpart * 16;
#pragma unroll
        for (int q = 0; q < 4; ++q) {
            float4 v = make_float4(T[cpart*16 + q*4 + 0][nw], T[cpart*16 + q*4 + 1][nw],
                                   T[cpart*16 + q*4 + 2][nw], T[cpart*16 + q*4 + 3][nw]);
            *reinterpret_cast<float4*>(&dst[q * 4]) = v;
        }
    }
}

// dist_mfma v2: split-bf16 MFMA filter with cooperative LDS A staging.
__global__ __launch_bounds__(256) void dist_mfma(
    const unsigned short* __restrict__ xnh, const unsigned short* __restrict__ xnl,
    float* __restrict__ dist, int bchunk)
{
    __shared__ float Ds[64][65];
    __shared__ unsigned short Ah[64 * 40];
    __shared__ unsigned short Al[64 * 40];
    const int bt = blockIdx.x;             // 0..90 (upper-triangle tiles)
    int rt = 0, rem = bt;
    while (rem >= 13 - rt) { rem -= 13 - rt; ++rt; }
    const int mt = rt + rem;
    const int bc = blockIdx.y;             // 0..15
    const int b  = bchunk * 16 + bc;
    const int r0 = rt * 64, m0 = mt * 64;
    const int tid = threadIdx.x;
    const int wv = tid >> 6, l = tid & 63;
    const int lm = l & 15, lk = l >> 4;

    const int mcol = m0 + wv * 16 + lm;
    const int mcl  = (mcol < Nn) ? mcol : (Nn - 1);
    const unsigned short* mh = xnh + ((size_t)b * Nn + mcl) * Cc;
    const unsigned short* ml = xnl + ((size_t)b * Nn + mcl) * Cc;

    const int srow = tid >> 2, spart = tid & 3;        // A staging task
    const int arow = r0 + srow;
    const int arowc = (arow < Nn) ? arow : (Nn - 1);
    const unsigned short* ah_src = xnh + ((size_t)b * Nn + arowc) * Cc;
    const unsigned short* al_src = xnl + ((size_t)b * Nn + arowc) * Cc;

    f32x4 acc[4];
#pragma unroll
    for (int mf = 0; mf < 4; ++mf) acc[mf] = (f32x4){0.f, 0.f, 0.f, 0.f};

#pragma unroll
    for (int ks = 0; ks < 6; ++ks) {
        const int k0 = ks * 32;
        bf16x8 bh = *reinterpret_cast<const bf16x8*>(&mh[k0 + lk * 8]);
        bf16x8 bl = *reinterpret_cast<const bf16x8*>(&ml[k0 + lk * 8]);
        __syncthreads();   // previous step's LDS reads complete
        *reinterpret_cast<bf16x8*>(&Ah[srow * 40 + spart * 8]) =
            *reinterpret_cast<const bf16x8*>(&ah_src[k0 + spart * 8]);
        *reinterpret_cast<bf16x8*>(&Al[srow * 40 + spart * 8]) =
            *reinterpret_cast<const bf16x8*>(&al_src[k0 + spart * 8]);
        __syncthreads();
#pragma unroll
        for (int mf = 0; mf < 4; ++mf) {
            bf16x8 ah = *reinterpret_cast<const bf16x8*>(&Ah[(mf * 16 + lm) * 40 + lk * 8]);
            bf16x8 al = *reinterpret_cast<const bf16x8*>(&Al[(mf * 16 + lm) * 40 + lk * 8]);
            acc[mf] = __builtin_amdgcn_mfma_f32_16x16x32_bf16(ah, bh, acc[mf], 0, 0, 0);
            acc[mf] = __builtin_amdgcn_mfma_f32_16x16x32_bf16(ah, bl, acc[mf], 0, 0, 0);
            acc[mf] = __builtin_amdgcn_mfma_f32_16x16x32_bf16(al, bh, acc[mf], 0, 0, 0);
        }
    }
    float* db = dist + (size_t)bc * Nn * Nn;
    __syncthreads();
#pragma unroll
    for (int mf = 0; mf < 4; ++mf) {
#pragma unroll
        for (int r = 0; r < 4; ++r) {
            const int rl = mf * 16 + lk * 4 + r;   // C/D: row=(l>>4)*4+r
            const float val = -acc[mf][r];
            Ds[rl][wv * 16 + lm] = val;            // col=lane&15
            const int rrow = r0 + rl;
            if (rrow < Nn && mcol < Nn)
                db[(size_t)rrow * Nn + mcol] = val;
        }
    }
    if (rt != mt) {
        __syncthreads();
        const int tx = tid & 15, ty = tid >> 4;
        const int rcol = r0 + tx * 4;              // full when rt<mt<=12
#pragma unroll
        for (int i = 0; i < 4; ++i) {
            const int mrow = m0 + ty * 4 + i;
            if (mrow < Nn) {
                float4 o = make_float4(Ds[tx*4+0][ty*4+i], Ds[tx*4+1][ty*4+i],
                                       Ds[tx*4+2][ty*4+i], Ds[tx*4+3][ty*4+i]);
                *reinterpret_cast<float4*>(&db[(size_t)mrow * Nn + rcol]) = o;
            }
        }
    }
}

// select16: one wave per row; 16x argmin-extract via shfl_xor. 16-batch chunks.
__global__ __launch_bounds__(256) void select16(
    const float* __restrict__ dist, int* __restrict__ cand,
    float* __restrict__ cdist, int bchunk)
{
    const int wid = blockIdx.x * 4 + (threadIdx.x >> 6);   // wave id in chunk
    const int L   = threadIdx.x & 63;
    const int r   = wid % Nn;
    const int bc  = wid / Nn;
    const int b   = bchunk * 16 + bc;
    const float* drow = dist + ((size_t)bc * Nn + r) * Nn;

    float v[13];
#pragma unroll
    for (int s = 0; s < 12; ++s) v[s] = drow[s * 64 + L];
    v[12] = (L < 16) ? drow[768 + L] : INFINITY;

    float mv = v[0]; int ms = 0;
#pragma unroll
    for (int s = 1; s < 13; ++s)
        if (v[s] < mv) { mv = v[s]; ms = s; }

    int out[16];
    float vals[16];
#pragma unroll
    for (int k = 0; k < 16; ++k) {
        float gv = mv; int gi = ms * 64 + L;
#pragma unroll
        for (int off = 1; off < 64; off <<= 1) {
            const float ov = __shfl_xor(gv, off, 64);
            const int   oi = __shfl_xor(gi, off, 64);
            if (ov < gv || (ov == gv && oi < gi)) { gv = ov; gi = oi; }
        }
        out[k] = gi; vals[k] = gv;
        const int ol = gi & 63, os = gi >> 6;
        if (L == ol) {
#pragma unroll
            for (int s = 0; s < 13; ++s) if (s == os) v[s] = INFINITY;
            mv = v[0]; ms = 0;
#pragma unroll
            for (int s = 1; s < 13; ++s)
                if (v[s] < mv) { mv = v[s]; ms = s; }
        }
    }
    if (L == 0) {
        int*   op = cand  + ((size_t)b * Nn + r) * 16;
        float* dp = cdist + ((size_t)b * Nn + r) * 16;
#pragma unroll
        for (int k = 0; k < 16; ++k) { op[k] = out[k]; dp[k] = vals[k]; }
    }
}

// zero_cnt: reset the ambiguous-row counter each launch (determinism).
__global__ void zero_cnt(int* cnt) { if (threadIdx.x == 0 && blockIdx.x == 0) *cnt = 0; }

// gap_route: clear-gap rows resolved directly from fast candidates; knife-edge
// rows appended to the ambiguous list.
__global__ __launch_bounds__(256) void gap_route(
    const int* __restrict__ cand, const float* __restrict__ cdist,
    int* __restrict__ nnidx, int* __restrict__ amb, int* __restrict__ cnt)
{
    const int idx = blockIdx.x * 256 + threadIdx.x;
    if (idx >= Bn * Nn) return;
    const float* dp = cdist + (size_t)idx * 16;
    const float d8 = dp[8], d9 = dp[9];
    if (d9 - d8 > GAP_DELTA) {
        const int* cp = cand + (size_t)idx * 16;
        int* op = nnidx + (size_t)idx * Kk;
#pragma unroll
        for (int k = 0; k < Kk; ++k) op[k] = cp[k];
    } else {
        const int pos = atomicAdd(cnt, 1);
        amb[pos] = idx;
    }
}

// refine_amb v3: one BLOCK per ambiguous row; reads the row-major xnT copy.
// BIT-EXACT sequential ascending-c add chain.
__global__ __launch_bounds__(256) void refine_amb(
    const float* __restrict__ xnT, const float* __restrict__ sq,
    const int* __restrict__ cand, const int* __restrict__ amb,
    const int* __restrict__ cnt, int* __restrict__ nnidx)
{
    __shared__ float prods[16][200];   // [cand][channel], padded
    __shared__ float Dd[16];
    __shared__ int   Dm[16];
    const int total = *cnt;
    const int k = threadIdx.x >> 4;    // candidate slot
    const int j = threadIdx.x & 15;    // channel segment

    for (int row = blockIdx.x; row < total; row += gridDim.x) {
        const int rowid = amb[row];
        const int b = rowid / Nn, r = rowid % Nn;
        const float* sqb = sq + (size_t)b * Nn;
        const int m = cand[(size_t)rowid * 16 + k];
        const float* rT = xnT + ((size_t)b * Nn + r) * Cc;
        const float* mT = xnT + ((size_t)b * Nn + m) * Cc;

#pragma unroll
        for (int i = 0; i < 12; ++i) {
            const int c = j * 12 + i;
            prods[k][c] = __fmul_rn(rT[c], mT[c]);
        }
        __syncthreads();
        if (j == 0) {
            float dot = 0.f;
            for (int c = 0; c < Cc; ++c)          // exact sequential chain
                dot = __fadd_rn(dot, prods[k][c]);
            const float t1 = __fmul_rn(2.f, dot);
            const float t2 = __fsub_rn(sqb[r], t1);
            Dd[k] = __fadd_rn(t2, sqb[m]);
            Dm[k] = m;
        }
        __syncthreads();
        if (threadIdx.x == 0) {
            float dl[16]; int il[16];
#pragma unroll
            for (int q = 0; q < 16; ++q) { dl[q] = Dd[q]; il[q] = Dm[q]; }
            int* op = nnidx + (size_t)rowid * Kk;
            for (int kk = 0; kk < Kk; ++kk) {
                int best = kk;
                for (int q = kk + 1; q < 16; ++q)
                    if (dl[q] < dl[best] || (dl[q] == dl[best] && il[q] < il[best])) best = q;
                float td = dl[kk]; dl[kk] = dl[best]; dl[best] = td;
                int ti = il[kk]; il[kk] = il[best]; il[best] = ti;
                op[kk] = il[kk];
            }
        }
        __syncthreads();
    }
}

// ===========================================================================
// VALUE PATH — bf16 MFMA (error budget 0.14; bf16 contributes ~0.03)
// ===========================================================================

// mr_pack v3: LDS-staged gather, packed bf16 transposed output (unchanged)
__global__ __launch_bounds__(256) void mr_pack(
    const float* __restrict__ xt, const int* __restrict__ nnidx,
    unsigned int* __restrict__ stT)
{
    __shared__ float rows[16][784];
    const int b   = blockIdx.y;
    const int c0  = blockIdx.x * 16;
    const int tid = threadIdx.x;
    const float* xb = xt + ((size_t)b * Cc + c0) * Nn;

#pragma unroll
    for (int c = 0; c < 16; ++c)
        for (int n = tid; n < Nn; n += 256)
            rows[c][n] = xb[(size_t)c * Nn + n];
    __syncthreads();

    for (int n = tid; n < Nn; n += 256) {
        const int* ip = nnidx + ((size_t)b * Nn + n) * Kk;
        int idx[Kk];
#pragma unroll
        for (int k = 0; k < Kk; ++k) idx[k] = ip[k];
        unsigned int pk[16];
#pragma unroll
        for (int c = 0; c < 16; ++c) {
            const float ctr = rows[c][n];
            float mx = -INFINITY;
#pragma unroll
            for (int k = 0; k < Kk; ++k)
                mx = fmaxf(mx, __fsub_rn(rows[c][idx[k]], ctr));
            pk[c] = (unsigned int)f2bf(ctr) | ((unsigned int)f2bf(mx) << 16);
        }
        unsigned int* dst = stT + ((size_t)b * Nn + n) * (C2c / 2) + c0;
#pragma unroll
        for (int q = 0; q < 4; ++q) {
            uint4 v = make_uint4(pk[q*4+0], pk[q*4+1], pk[q*4+2], pk[q*4+3]);
            *reinterpret_cast<uint4*>(&dst[q * 4]) = v;
        }
    }
}

__global__ __launch_bounds__(256) void wcvt(
    const float* __restrict__ w, unsigned short* __restrict__ wbf, int nElem)
{
    const int i = blockIdx.x * 256 + threadIdx.x;
    if (i < nElem) wbf[i] = f2bf(w[i]);
}

// gconv_mfma (unchanged)
__global__ __launch_bounds__(256) void gconv_mfma(
    const unsigned short* __restrict__ stT, const unsigned short* __restrict__ wbf2,
    const float* __restrict__ gb,
    const float* __restrict__ gg, const float* __restrict__ bb_,
    const float* __restrict__ mm, const float* __restrict__ vv,
    unsigned short* __restrict__ gT)
{
    const int b   = blockIdx.z;
    const int grp = blockIdx.y;
    const int n0  = blockIdx.x * 64;
    const int tid = threadIdx.x;
    const int wv  = tid >> 6;
    const int l   = tid & 63;
    const int lm  = l & 15, lk = l >> 4;

    const int ncol = n0 + wv * 16 + lm;
    const int ncl  = (ncol < Nn) ? ncol : (Nn - 1);
    const unsigned short* gRow = stT + ((size_t)b * Nn + ncl) * C2c + grp * 96;

    f32x4 acc[6];
#pragma unroll
    for (int mf = 0; mf < 6; ++mf) acc[mf] = (f32x4){0.f, 0.f, 0.f, 0.f};

#pragma unroll
    for (int k0 = 0; k0 < 96; k0 += 32) {
        bf16x8 bfr = *reinterpret_cast<const bf16x8*>(&gRow[k0 + lk * 8]);
#pragma unroll
        for (int mf = 0; mf < 6; ++mf) {
            bf16x8 afr = *reinterpret_cast<const bf16x8*>(
                &wbf2[((size_t)grp * 96 + mf * 16 + lm) * 96 + k0 + lk * 8]);
            acc[mf] = __builtin_amdgcn_mfma_f32_16x16x32_bf16(afr, bfr, acc[mf], 0, 0, 0);
        }
    }
    if (ncol < Nn) {
#pragma unroll
        for (int mf = 0; mf < 6; ++mf) {
            unsigned long long pk = 0ull;
#pragma unroll
            for (int r = 0; r < 4; ++r) {
                const int oc = grp * 96 + mf * 16 + lk * 4 + r;
                const float s  = gg[oc] * rsqrtf(vv[oc] + 1e-5f);
                const float sh = (gb[oc] - mm[oc]) * s + bb_[oc];
                float v = fmaf(acc[mf][r], s, sh);
                float ge = 0.5f * v * (1.f + erff(v * 0.70710678118654752f));
                pk |= ((unsigned long long)f2bf(ge)) << (16 * r);
            }
            *reinterpret_cast<unsigned long long*>(
                &gT[((size_t)b * Nn + ncol) * C2c + grp * 96 + mf * 16 + lk * 4]) = pk;
        }
    }
}

// fc2_mfma v3 (unchanged): LDS-staged weight k-slices
__global__ __launch_bounds__(256) void fc2_mfma(
    const unsigned short* __restrict__ gT, const unsigned short* __restrict__ wbf,
    const float* __restrict__ bias,
    const float* __restrict__ gg, const float* __restrict__ bb_,
    const float* __restrict__ mm, const float* __restrict__ vv,
    const float* __restrict__ xres,
    float* __restrict__ out)
{
    __shared__ float sS[192], sH[192];
    __shared__ unsigned short sW[192 * 40];
    const int b   = blockIdx.y;
    const int n0  = blockIdx.x * 64;
    const int tid = threadIdx.x;
    const int wv  = tid >> 6;
    const int l   = tid & 63;
    const int lm  = l & 15, lk = l >> 4;

    if (tid < 192) {
        const float s = gg[tid] * rsqrtf(vv[tid] + 1e-5f);
        sS[tid] = s;
        sH[tid] = (bias[tid] - mm[tid]) * s + bb_[tid];
    }

    const int ncol = n0 + wv * 16 + lm;
    const int ncl  = (ncol < Nn) ? ncol : (Nn - 1);
    const unsigned short* gRow = gT + ((size_t)b * Nn + ncl) * C2c;

    f32x4 acc[12];
#pragma unroll
    for (int mf = 0; mf < 12; ++mf) acc[mf] = (f32x4){0.f, 0.f, 0.f, 0.f};

    const int srow = tid >> 2, spart = tid & 3;
    for (int ks = 0; ks < 12; ++ks) {
        const int k0 = ks * 32;
        bf16x8 bfr = *reinterpret_cast<const bf16x8*>(&gRow[k0 + lk * 8]);
        __syncthreads();
#pragma unroll
        for (int p = 0; p < 3; ++p) {
            const int row = srow + p * 64;
            *reinterpret_cast<bf16x8*>(&sW[row * 40 + spart * 8]) =
                *reinterpret_cast<const bf16x8*>(&wbf[(size_t)row * C2c + k0 + spart * 8]);
        }
        __syncthreads();
#pragma unroll
        for (int mf = 0; mf < 12; ++mf) {
            bf16x8 afr = *reinterpret_cast<const bf16x8*>(&sW[(mf * 16 + lm) * 40 + lk * 8]);
            acc[mf] = __builtin_amdgcn_mfma_f32_16x16x32_bf16(afr, bfr, acc[mf], 0, 0, 0);
        }
    }
    if (ncol < Nn) {
#pragma unroll
        for (int mf = 0; mf < 12; ++mf) {
#pragma unroll
            for (int r = 0; r < 4; ++r) {
                const int o = mf * 16 + lk * 4 + r;   // C/D: row=(l>>4)*4+r
                const size_t oi = ((size_t)b * Cc + o) * Nn + ncol;  // col=lane&15
                out[oi] = fmaf(acc[mf][r], sS[o], sH[o]) + xres[oi];
            }
        }
    }
}

// ---------------------------------------------------------------------------
extern "C" void kernel_launch(void* const* d_in, const int* in_sizes, int n_in,
                              void* d_out, int out_size, void* d_ws, size_t ws_size,
                              hipStream_t stream)
{
    const float* x     = (const float*)d_in[0];
    const float* fc1_w = (const float*)d_in[1];
    const float* fc1_b = (const float*)d_in[2];
    const float* bn1_g = (const float*)d_in[3];
    const float* bn1_b = (const float*)d_in[4];
    const float* bn1_m = (const float*)d_in[5];
    const float* bn1_v = (const float*)d_in[6];
    const float* gc_w  = (const float*)d_in[7];
    const float* gc_b  = (const float*)d_in[8];
    const float* bn2_g = (const float*)d_in[9];
    const float* bn2_b = (const float*)d_in[10];
    const float* bn2_m = (const float*)d_in[11];
    const float* bn2_v = (const float*)d_in[12];
    const float* fc2_w = (const float*)d_in[13];
    const float* fc2_b = (const float*)d_in[14];
    const float* bn3_g = (const float*)d_in[15];
    const float* bn3_b = (const float*)d_in[16];
    const float* bn3_m = (const float*)d_in[17];
    const float* bn3_v = (const float*)d_in[18];

    float* out = (float*)d_out;                  // xt scratch, overwritten by fc2

    // workspace layout (identical to round 21, proven):
    char* wsb = (char*)d_ws;
    const size_t regionBytes = (size_t)Bn * C2c * Nn * 4;    // 77,070,336
    const size_t distBytes   = (size_t)16 * Nn * Nn * 4;     // 39,337,984
    float* dist = (float*)wsb;
    unsigned short* xnh = (unsigned short*)(wsb + distBytes);
    float* xnT  = (float*)wsb;
    unsigned int*   stT32 = (unsigned int*)wsb;
    unsigned short* stT   = (unsigned short*)wsb;
    char*  g2   = wsb + regionBytes;
    float* xnb  = (float*)g2;                                      // 38,535,168 B
    float* sqb  = (float*)(g2 + (size_t)Bn * Cc * Nn * 4);         // 200,704 B
    int*   c16  = (int*)(g2 + (size_t)Bn * Cc * Nn * 4 + 200704);  // 3,211,264 B
    float* cd16 = (float*)(g2 + (size_t)Bn * Cc * Nn * 4 + 200704 + 3211264); // 3,211,264 B
    unsigned short* gT   = (unsigned short*)g2;                    // bf16, aliases xn
    unsigned short* wbf  = (unsigned short*)(g2 + 45158912);       // 147,456 B
    unsigned short* wbf2 = (unsigned short*)(g2 + 45158912 + 147456); // 73,728 B
    unsigned short* xnl  = (unsigned short*)(g2 + 45158912 + 147456 + 73728); // 19,267,584 B
    char*  g3   = wsb + 2 * regionBytes;
    int*   nni  = (int*)g3;                                        // 1,806,336 B
    int*   amb  = (int*)(g3 + 1806336);                            // 200,704 B
    int*   cnt  = (int*)(g3 + 1806336 + 200704);                   // 4 B

    const int nBN = Bn * Nn;

    dim3 blk(256);
    wcvt<<<dim3((Cc * C2c + 255) / 256), blk, 0, stream>>>(fc2_w, wbf, Cc * C2c);
    wcvt<<<dim3((4 * 96 * 96 + 255) / 256), blk, 0, stream>>>(gc_w, wbf2, 4 * 96 * 96);
    fc1_np<<<dim3(7, 3, Bn), blk, 0, stream>>>(
        x, fc1_w, fc1_b, bn1_g, bn1_b, bn1_m, bn1_v, out);
    norm_np<<<dim3((nBN + 255) / 256), blk, 0, stream>>>(out, xnb, sqb);
    xpose_bf<<<dim3(13, 3, Bn), blk, 0, stream>>>(xnb, xnh, xnl);
    for (int ch = 0; ch < 4; ++ch) {
        dist_mfma<<<dim3(91, 16), blk, 0, stream>>>(xnh, xnl, dist, ch);
        select16<<<dim3(16 * Nn / 4), blk, 0, stream>>>(dist, c16, cd16, ch);
    }
    xpose_f32<<<dim3(13, 3, Bn), blk, 0, stream>>>(xnb, xnT);
    zero_cnt<<<dim3(1), dim3(64), 0, stream>>>(cnt);
    gap_route<<<dim3((nBN + 255) / 256), blk, 0, stream>>>(c16, cd16, nni, amb, cnt);
    refine_amb<<<dim3(784), blk, 0, stream>>>(xnT, sqb, c16, amb, cnt, nni);
    mr_pack<<<dim3(12, Bn), blk, 0, stream>>>(out, nni, stT32);
    gconv_mfma<<<dim3(13, 4, Bn), blk, 0, stream>>>(
        stT, wbf2, gc_b, bn2_g, bn2_b, bn2_m, bn2_v, gT);
    fc2_mfma<<<dim3(13, Bn), blk, 0, stream>>>(
        gT, wbf, fc2_b, bn3_g, bn3_b, bn3_m, bn3_v, x, out);
}

// Round 23
// 522.320 us; speedup vs baseline: 1.3352x; 1.0545x over previous
//
#include <hip/hip_runtime.h>
#include <math.h>

static constexpr int Bn  = 64;    // batch
static constexpr int Cc  = 192;   // channels
static constexpr int Nn  = 784;   // H*W
static constexpr int C2c = 384;   // 2C
static constexpr int Kk  = 9;     // knn K
#define GAP_DELTA 1e-4f

typedef __attribute__((ext_vector_type(8))) short bf16x8;
typedef __attribute__((ext_vector_type(4))) float f32x4;

__device__ inline unsigned short f2bf(float f) {   // RNE f32 -> bf16
    unsigned int u = __float_as_uint(f);
    return (unsigned short)((u + 0x7FFFu + ((u >> 16) & 1u)) >> 16);
}

// ===========================================================================
// INDEX PATH — np-f32 bit-exact where values matter (fc1, norm, refine_amb).
// ===========================================================================

// fc1_np: BIT-CRITICAL — numpy-f32-exact (no FMA, ascending-c accumulation).
// 64(o) x 128(n) tile, 4x8 per thread (proven conflict-free pattern).
__global__ __launch_bounds__(256) void fc1_np(
    const float* __restrict__ x, const float* __restrict__ w,
    const float* __restrict__ bias,
    const float* __restrict__ gg, const float* __restrict__ bb_,
    const float* __restrict__ mm, const float* __restrict__ vv,
    float* __restrict__ xt)
{
    __shared__ float As[16][64];
    __shared__ float Bs[16][128];
    const int b   = blockIdx.z;
    const int n0  = blockIdx.x * 128;
    const int o0  = blockIdx.y * 64;
    const int tid = threadIdx.x;
    const int tx = tid & 15, ty = tid >> 4;
    const int lo = tid & 63, lk4 = tid >> 6;
    const int ln4 = tid & 15, lbk = tid >> 4;
    const float* xb = x + (size_t)b * Cc * Nn;

    float acc[4][8];
#pragma unroll
    for (int i = 0; i < 4; ++i)
#pragma unroll
        for (int j = 0; j < 8; ++j) acc[i][j] = 0.f;

    for (int kt = 0; kt < 12; ++kt) {               // c ascending: kt*16 + kk
        const int k0 = kt * 16;
        float4 av = *reinterpret_cast<const float4*>(&w[(size_t)(o0 + lo) * 192 + k0 + lk4 * 4]);
        As[lk4*4+0][lo] = av.x;
        As[lk4*4+1][lo] = av.y;
        As[lk4*4+2][lo] = av.z;
        As[lk4*4+3][lo] = av.w;
        const int na = n0 + ln4 * 4;
        const int nb = n0 + 64 + ln4 * 4;
        float4 b0 = make_float4(0.f, 0.f, 0.f, 0.f);
        float4 b1 = make_float4(0.f, 0.f, 0.f, 0.f);
        if (na < Nn) b0 = *reinterpret_cast<const float4*>(&xb[(size_t)(k0 + lbk) * Nn + na]);
        if (nb < Nn) b1 = *reinterpret_cast<const float4*>(&xb[(size_t)(k0 + lbk) * Nn + nb]);
        *reinterpret_cast<float4*>(&Bs[lbk][ln4*4])      = b0;
        *reinterpret_cast<float4*>(&Bs[lbk][64 + ln4*4]) = b1;
        __syncthreads();
#pragma unroll
        for (int kk = 0; kk < 16; ++kk) {
            float ar[4], br[8];
#pragma unroll
            for (int i = 0; i < 4; ++i) ar[i] = As[kk][ty*4+i];
#pragma unroll
            for (int j = 0; j < 4; ++j) br[j]     = Bs[kk][tx*4+j];
#pragma unroll
            for (int j = 0; j < 4; ++j) br[4 + j] = Bs[kk][64 + tx*4+j];
#pragma unroll
            for (int i = 0; i < 4; ++i)
#pragma unroll
                for (int j = 0; j < 8; ++j)
                    acc[i][j] = __fadd_rn(acc[i][j], __fmul_rn(ar[i], br[j]));
        }
        __syncthreads();
    }
    const int na = n0 + tx * 4;
    const int nb = n0 + 64 + tx * 4;
#pragma unroll
    for (int i = 0; i < 4; ++i) {
        const int o = o0 + ty * 4 + i;
        const float e  = __fadd_rn(vv[o], 1e-5f);
        const float r1 = __fsqrt_rn(e);
        const float rr = __fdiv_rn(1.f, r1);
        const float s  = __fmul_rn(gg[o], rr);
        const size_t rowb = ((size_t)b * Cc + o) * Nn;
        if (na < Nn) {
#pragma unroll
            for (int j = 0; j < 4; ++j) {
                const float h = __fadd_rn(acc[i][j], bias[o]);
                const float t = __fsub_rn(h, mm[o]);
                const float u = __fmul_rn(t, s);
                xt[rowb + na + j] = __fadd_rn(u, bb_[o]);
            }
        }
        if (nb < Nn) {
#pragma unroll
            for (int j = 0; j < 4; ++j) {
                const float h = __fadd_rn(acc[i][4 + j], bias[o]);
                const float t = __fsub_rn(h, mm[o]);
                const float u = __fmul_rn(t, s);
                xt[rowb + nb + j] = __fadd_rn(u, bb_[o]);
            }
        }
    }
}

// norm_fuse: BIT-CRITICAL arithmetic. One kernel replaces norm_np + xpose_bf
// + xpose_f32. Block = (b, 64-n tile); xt tile staged in LDS; per-pixel
// np-exact norm chain; in-place exact division; np-pairwise sq; emits
// split-bf16 xnh/xnl and f32 xnT, all row-major [b][n][c]. Col-major xn
// is never materialized (nothing consumes it).
__global__ __launch_bounds__(256) void norm_fuse(
    const float* __restrict__ xt,
    unsigned short* __restrict__ xnh, unsigned short* __restrict__ xnl,
    float* __restrict__ xnT, float* __restrict__ sq)
{
    __shared__ float T[192][65];
    __shared__ float nrmv[64];
    const int b   = blockIdx.y;
    const int n0  = blockIdx.x * 64;
    const int tid = threadIdx.x;
    const float* xb = xt + (size_t)b * Cc * Nn;

    // load tile (Nn % 4 == 0 -> float4 guard by base index)
    for (int t = tid; t < 192 * 16; t += 256) {
        const int c = t >> 4, part = t & 15;
        const int n = n0 + part * 4;
        float4 v = make_float4(0.f, 0.f, 0.f, 0.f);
        if (n < Nn) v = *reinterpret_cast<const float4*>(&xb[(size_t)c * Nn + n]);
        T[c][part*4+0] = v.x; T[c][part*4+1] = v.y;
        T[c][part*4+2] = v.z; T[c][part*4+3] = v.w;
    }
    __syncthreads();

    // np-exact norm chain per pixel (sequential ascending c)
    if (tid < 64) {
        const int n = n0 + tid;
        float nrm = 1.f;
        if (n < Nn) {
            float acc = 0.f;
            for (int c = 0; c < Cc; ++c) {
                const float v = T[c][tid];
                acc = __fadd_rn(acc, __fmul_rn(v, v));
            }
            nrm = __fsqrt_rn(acc);
            nrm = fmaxf(nrm, 1e-12f);
        }
        nrmv[tid] = nrm;
    }
    __syncthreads();

    // in-place exact division (same bits as np's x / nrm)
    for (int t = tid; t < 192 * 64; t += 256) {
        const int c = t >> 6, nl = t & 63;
        T[c][nl] = __fdiv_rn(T[c][nl], nrmv[nl]);
    }
    __syncthreads();

    // np-pairwise sq from divided values (96+96 split, 8-way unroll)
    if (tid < 64) {
        const int n = n0 + tid;
        if (n < Nn) {
            float sblk[2];
#pragma unroll
            for (int blk = 0; blk < 2; ++blk) {
                const int base = blk * 96;
                float r[8];
#pragma unroll
                for (int j = 0; j < 8; ++j) {
                    const float xv = T[base + j][tid];
                    r[j] = __fmul_rn(xv, xv);
                }
                for (int i = 8; i < 96; i += 8) {
#pragma unroll
                    for (int j = 0; j < 8; ++j) {
                        const float xv = T[base + i + j][tid];
                        r[j] = __fadd_rn(r[j], __fmul_rn(xv, xv));
                    }
                }
                sblk[blk] = __fadd_rn(
                    __fadd_rn(__fadd_rn(r[0], r[1]), __fadd_rn(r[2], r[3])),
                    __fadd_rn(__fadd_rn(r[4], r[5]), __fadd_rn(r[6], r[7])));
            }
            sq[b * Nn + n] = __fadd_rn(sblk[0], sblk[1]);
        }
    }

    // row-major outputs: 4 threads per pixel, each owns 48 channels
    const int nw = tid >> 2, cpart = tid & 3;
    const int n = n0 + nw;
    if (n < Nn) {
        const int cbase = cpart * 48;
        // xnT f32
        float* dT = xnT + ((size_t)b * Nn + n) * Cc + cbase;
#pragma unroll
        for (int q = 0; q < 12; ++q) {
            float4 v = make_float4(T[cbase + q*4 + 0][nw], T[cbase + q*4 + 1][nw],
                                   T[cbase + q*4 + 2][nw], T[cbase + q*4 + 3][nw]);
            *reinterpret_cast<float4*>(&dT[q * 4]) = v;
        }
        // split-bf16
        unsigned short hbuf[48], lbuf[48];
#pragma unroll
        for (int j = 0; j < 48; ++j) {
            const float v = T[cbase + j][nw];
            const unsigned short h = f2bf(v);
            const float hf = __uint_as_float(((unsigned int)h) << 16);
            hbuf[j] = h;
            lbuf[j] = f2bf(__fsub_rn(v, hf));
        }
        unsigned short* dh = xnh + ((size_t)b * Nn + n) * Cc + cbase;
        unsigned short* dl = xnl + ((size_t)b * Nn + n) * Cc + cbase;
#pragma unroll
        for (int q = 0; q < 6; ++q) {
            *reinterpret_cast<bf16x8*>(&dh[q * 8]) = *reinterpret_cast<bf16x8*>(&hbuf[q * 8]);
            *reinterpret_cast<bf16x8*>(&dl[q * 8]) = *reinterpret_cast<bf16x8*>(&lbuf[q * 8]);
        }
    }
}

// dist_mfma v2: split-bf16 MFMA filter with cooperative LDS A staging.
__global__ __launch_bounds__(256) void dist_mfma(
    const unsigned short* __restrict__ xnh, const unsigned short* __restrict__ xnl,
    float* __restrict__ dist, int bchunk)
{
    __shared__ float Ds[64][65];
    __shared__ unsigned short Ah[64 * 40];
    __shared__ unsigned short Al[64 * 40];
    const int bt = blockIdx.x;             // 0..90 (upper-triangle tiles)
    int rt = 0, rem = bt;
    while (rem >= 13 - rt) { rem -= 13 - rt; ++rt; }
    const int mt = rt + rem;
    const int bc = blockIdx.y;             // 0..15
    const int b  = bchunk * 16 + bc;
    const int r0 = rt * 64, m0 = mt * 64;
    const int tid = threadIdx.x;
    const int wv = tid >> 6, l = tid & 63;
    const int lm = l & 15, lk = l >> 4;

    const int mcol = m0 + wv * 16 + lm;
    const int mcl  = (mcol < Nn) ? mcol : (Nn - 1);
    const unsigned short* mh = xnh + ((size_t)b * Nn + mcl) * Cc;
    const unsigned short* ml = xnl + ((size_t)b * Nn + mcl) * Cc;

    const int srow = tid >> 2, spart = tid & 3;        // A staging task
    const int arow = r0 + srow;
    const int arowc = (arow < Nn) ? arow : (Nn - 1);
    const unsigned short* ah_src = xnh + ((size_t)b * Nn + arowc) * Cc;
    const unsigned short* al_src = xnl + ((size_t)b * Nn + arowc) * Cc;

    f32x4 acc[4];
#pragma unroll
    for (int mf = 0; mf < 4; ++mf) acc[mf] = (f32x4){0.f, 0.f, 0.f, 0.f};

#pragma unroll
    for (int ks = 0; ks < 6; ++ks) {
        const int k0 = ks * 32;
        bf16x8 bh = *reinterpret_cast<const bf16x8*>(&mh[k0 + lk * 8]);
        bf16x8 bl = *reinterpret_cast<const bf16x8*>(&ml[k0 + lk * 8]);
        __syncthreads();   // previous step's LDS reads complete
        *reinterpret_cast<bf16x8*>(&Ah[srow * 40 + spart * 8]) =
            *reinterpret_cast<const bf16x8*>(&ah_src[k0 + spart * 8]);
        *reinterpret_cast<bf16x8*>(&Al[srow * 40 + spart * 8]) =
            *reinterpret_cast<const bf16x8*>(&al_src[k0 + spart * 8]);
        __syncthreads();
#pragma unroll
        for (int mf = 0; mf < 4; ++mf) {
            bf16x8 ah = *reinterpret_cast<const bf16x8*>(&Ah[(mf * 16 + lm) * 40 + lk * 8]);
            bf16x8 al = *reinterpret_cast<const bf16x8*>(&Al[(mf * 16 + lm) * 40 + lk * 8]);
            acc[mf] = __builtin_amdgcn_mfma_f32_16x16x32_bf16(ah, bh, acc[mf], 0, 0, 0);
            acc[mf] = __builtin_amdgcn_mfma_f32_16x16x32_bf16(ah, bl, acc[mf], 0, 0, 0);
            acc[mf] = __builtin_amdgcn_mfma_f32_16x16x32_bf16(al, bh, acc[mf], 0, 0, 0);
        }
    }
    float* db = dist + (size_t)bc * Nn * Nn;
    __syncthreads();
#pragma unroll
    for (int mf = 0; mf < 4; ++mf) {
#pragma unroll
        for (int r = 0; r < 4; ++r) {
            const int rl = mf * 16 + lk * 4 + r;   // C/D: row=(l>>4)*4+r
            const float val = -acc[mf][r];
            Ds[rl][wv * 16 + lm] = val;            // col=lane&15
            const int rrow = r0 + rl;
            if (rrow < Nn && mcol < Nn)
                db[(size_t)rrow * Nn + mcol] = val;
        }
    }
    if (rt != mt) {
        __syncthreads();
        const int tx = tid & 15, ty = tid >> 4;
        const int rcol = r0 + tx * 4;              // full when rt<mt<=12
#pragma unroll
        for (int i = 0; i < 4; ++i) {
            const int mrow = m0 + ty * 4 + i;
            if (mrow < Nn) {
                float4 o = make_float4(Ds[tx*4+0][ty*4+i], Ds[tx*4+1][ty*4+i],
                                       Ds[tx*4+2][ty*4+i], Ds[tx*4+3][ty*4+i]);
                *reinterpret_cast<float4*>(&db[(size_t)mrow * Nn + rcol]) = o;
            }
        }
    }
}

// select16: one wave per row; 16x argmin-extract via shfl_xor. 16-batch chunks.
__global__ __launch_bounds__(256) void select16(
    const float* __restrict__ dist, int* __restrict__ cand,
    float* __restrict__ cdist, int bchunk)
{
    const int wid = blockIdx.x * 4 + (threadIdx.x >> 6);   // wave id in chunk
    const int L   = threadIdx.x & 63;
    const int r   = wid % Nn;
    const int bc  = wid / Nn;
    const int b   = bchunk * 16 + bc;
    const float* drow = dist + ((size_t)bc * Nn + r) * Nn;

    float v[13];
#pragma unroll
    for (int s = 0; s < 12; ++s) v[s] = drow[s * 64 + L];
    v[12] = (L < 16) ? drow[768 + L] : INFINITY;

    float mv = v[0]; int ms = 0;
#pragma unroll
    for (int s = 1; s < 13; ++s)
        if (v[s] < mv) { mv = v[s]; ms = s; }

    int out[16];
    float vals[16];
#pragma unroll
    for (int k = 0; k < 16; ++k) {
        float gv = mv; int gi = ms * 64 + L;
#pragma unroll
        for (int off = 1; off < 64; off <<= 1) {
            const float ov = __shfl_xor(gv, off, 64);
            const int   oi = __shfl_xor(gi, off, 64);
            if (ov < gv || (ov == gv && oi < gi)) { gv = ov; gi = oi; }
        }
        out[k] = gi; vals[k] = gv;
        const int ol = gi & 63, os = gi >> 6;
        if (L == ol) {
#pragma unroll
            for (int s = 0; s < 13; ++s) if (s == os) v[s] = INFINITY;
            mv = v[0]; ms = 0;
#pragma unroll
            for (int s = 1; s < 13; ++s)
                if (v[s] < mv) { mv = v[s]; ms = s; }
        }
    }
    if (L == 0) {
        int*   op = cand  + ((size_t)b * Nn + r) * 16;
        float* dp = cdist + ((size_t)b * Nn + r) * 16;
#pragma unroll
        for (int k = 0; k < 16; ++k) { op[k] = out[k]; dp[k] = vals[k]; }
    }
}

// zero_cnt: reset the ambiguous-row counter each launch (determinism).
__global__ void zero_cnt(int* cnt) { if (threadIdx.x == 0 && blockIdx.x == 0) *cnt = 0; }

// gap_route: clear-gap rows resolved directly from fast candidates; knife-edge
// rows appended to the ambiguous list.
__global__ __launch_bounds__(256) void gap_route(
    const int* __restrict__ cand, const float* __restrict__ cdist,
    int* __restrict__ nnidx, int* __restrict__ amb, int* __restrict__ cnt)
{
    const int idx = blockIdx.x * 256 + threadIdx.x;
    if (idx >= Bn * Nn) return;
    const float* dp = cdist + (size_t)idx * 16;
    const float d8 = dp[8], d9 = dp[9];
    if (d9 - d8 > GAP_DELTA) {
        const int* cp = cand + (size_t)idx * 16;
        int* op = nnidx + (size_t)idx * Kk;
#pragma unroll
        for (int k = 0; k < Kk; ++k) op[k] = cp[k];
    } else {
        const int pos = atomicAdd(cnt, 1);
        amb[pos] = idx;
    }
}

// refine_amb v3: one BLOCK per ambiguous row; reads the row-major xnT copy.
// BIT-EXACT sequential ascending-c add chain.
__global__ __launch_bounds__(256) void refine_amb(
    const float* __restrict__ xnT, const float* __restrict__ sq,
    const int* __restrict__ cand, const int* __restrict__ amb,
    const int* __restrict__ cnt, int* __restrict__ nnidx)
{
    __shared__ float prods[16][200];   // [cand][channel], padded
    __shared__ float Dd[16];
    __shared__ int   Dm[16];
    const int total = *cnt;
    const int k = threadIdx.x >> 4;    // candidate slot
    const int j = threadIdx.x & 15;    // channel segment

    for (int row = blockIdx.x; row < total; row += gridDim.x) {
        const int rowid = amb[row];
        const int b = rowid / Nn, r = rowid % Nn;
        const float* sqb = sq + (size_t)b * Nn;
        const int m = cand[(size_t)rowid * 16 + k];
        const float* rT = xnT + ((size_t)b * Nn + r) * Cc;
        const float* mT = xnT + ((size_t)b * Nn + m) * Cc;

#pragma unroll
        for (int i = 0; i < 12; ++i) {
            const int c = j * 12 + i;
            prods[k][c] = __fmul_rn(rT[c], mT[c]);
        }
        __syncthreads();
        if (j == 0) {
            float dot = 0.f;
            for (int c = 0; c < Cc; ++c)          // exact sequential chain
                dot = __fadd_rn(dot, prods[k][c]);
            const float t1 = __fmul_rn(2.f, dot);
            const float t2 = __fsub_rn(sqb[r], t1);
            Dd[k] = __fadd_rn(t2, sqb[m]);
            Dm[k] = m;
        }
        __syncthreads();
        if (threadIdx.x == 0) {
            float dl[16]; int il[16];
#pragma unroll
            for (int q = 0; q < 16; ++q) { dl[q] = Dd[q]; il[q] = Dm[q]; }
            int* op = nnidx + (size_t)rowid * Kk;
            for (int kk = 0; kk < Kk; ++kk) {
                int best = kk;
                for (int q = kk + 1; q < 16; ++q)
                    if (dl[q] < dl[best] || (dl[q] == dl[best] && il[q] < il[best])) best = q;
                float td = dl[kk]; dl[kk] = dl[best]; dl[best] = td;
                int ti = il[kk]; il[kk] = il[best]; il[best] = ti;
                op[kk] = il[kk];
            }
        }
        __syncthreads();
    }
}

// ===========================================================================
// VALUE PATH — bf16 MFMA (error budget 0.14; bf16 contributes ~0.03)
// ===========================================================================

// mr_pack v3: LDS-staged gather, packed bf16 transposed output (unchanged)
__global__ __launch_bounds__(256) void mr_pack(
    const float* __restrict__ xt, const int* __restrict__ nnidx,
    unsigned int* __restrict__ stT)
{
    __shared__ float rows[16][784];
    const int b   = blockIdx.y;
    const int c0  = blockIdx.x * 16;
    const int tid = threadIdx.x;
    const float* xb = xt + ((size_t)b * Cc + c0) * Nn;

#pragma unroll
    for (int c = 0; c < 16; ++c)
        for (int n = tid; n < Nn; n += 256)
            rows[c][n] = xb[(size_t)c * Nn + n];
    __syncthreads();

    for (int n = tid; n < Nn; n += 256) {
        const int* ip = nnidx + ((size_t)b * Nn + n) * Kk;
        int idx[Kk];
#pragma unroll
        for (int k = 0; k < Kk; ++k) idx[k] = ip[k];
        unsigned int pk[16];
#pragma unroll
        for (int c = 0; c < 16; ++c) {
            const float ctr = rows[c][n];
            float mx = -INFINITY;
#pragma unroll
            for (int k = 0; k < Kk; ++k)
                mx = fmaxf(mx, __fsub_rn(rows[c][idx[k]], ctr));
            pk[c] = (unsigned int)f2bf(ctr) | ((unsigned int)f2bf(mx) << 16);
        }
        unsigned int* dst = stT + ((size_t)b * Nn + n) * (C2c / 2) + c0;
#pragma unroll
        for (int q = 0; q < 4; ++q) {
            uint4 v = make_uint4(pk[q*4+0], pk[q*4+1], pk[q*4+2], pk[q*4+3]);
            *reinterpret_cast<uint4*>(&dst[q * 4]) = v;
        }
    }
}

__global__ __launch_bounds__(256) void wcvt(
    const float* __restrict__ w, unsigned short* __restrict__ wbf, int nElem)
{
    const int i = blockIdx.x * 256 + threadIdx.x;
    if (i < nElem) wbf[i] = f2bf(w[i]);
}

// gconv_mfma (unchanged)
__global__ __launch_bounds__(256) void gconv_mfma(
    const unsigned short* __restrict__ stT, const unsigned short* __restrict__ wbf2,
    const float* __restrict__ gb,
    const float* __restrict__ gg, const float* __restrict__ bb_,
    const float* __restrict__ mm, const float* __restrict__ vv,
    unsigned short* __restrict__ gT)
{
    const int b   = blockIdx.z;
    const int grp = blockIdx.y;
    const int n0  = blockIdx.x * 64;
    const int tid = threadIdx.x;
    const int wv  = tid >> 6;
    const int l   = tid & 63;
    const int lm  = l & 15, lk = l >> 4;

    const int ncol = n0 + wv * 16 + lm;
    const int ncl  = (ncol < Nn) ? ncol : (Nn - 1);
    const unsigned short* gRow = stT + ((size_t)b * Nn + ncl) * C2c + grp * 96;

    f32x4 acc[6];
#pragma unroll
    for (int mf = 0; mf < 6; ++mf) acc[mf] = (f32x4){0.f, 0.f, 0.f, 0.f};

#pragma unroll
    for (int k0 = 0; k0 < 96; k0 += 32) {
        bf16x8 bfr = *reinterpret_cast<const bf16x8*>(&gRow[k0 + lk * 8]);
#pragma unroll
        for (int mf = 0; mf < 6; ++mf) {
            bf16x8 afr = *reinterpret_cast<const bf16x8*>(
                &wbf2[((size_t)grp * 96 + mf * 16 + lm) * 96 + k0 + lk * 8]);
            acc[mf] = __builtin_amdgcn_mfma_f32_16x16x32_bf16(afr, bfr, acc[mf], 0, 0, 0);
        }
    }
    if (ncol < Nn) {
#pragma unroll
        for (int mf = 0; mf < 6; ++mf) {
            unsigned long long pk = 0ull;
#pragma unroll
            for (int r = 0; r < 4; ++r) {
                const int oc = grp * 96 + mf * 16 + lk * 4 + r;
                const float s  = gg[oc] * rsqrtf(vv[oc] + 1e-5f);
                const float sh = (gb[oc] - mm[oc]) * s + bb_[oc];
                float v = fmaf(acc[mf][r], s, sh);
                float ge = 0.5f * v * (1.f + erff(v * 0.70710678118654752f));
                pk |= ((unsigned long long)f2bf(ge)) << (16 * r);
            }
            *reinterpret_cast<unsigned long long*>(
                &gT[((size_t)b * Nn + ncol) * C2c + grp * 96 + mf * 16 + lk * 4]) = pk;
        }
    }
}

// fc2_mfma v3 (unchanged): LDS-staged weight k-slices
__global__ __launch_bounds__(256) void fc2_mfma(
    const unsigned short* __restrict__ gT, const unsigned short* __restrict__ wbf,
    const float* __restrict__ bias,
    const float* __restrict__ gg, const float* __restrict__ bb_,
    const float* __restrict__ mm, const float* __restrict__ vv,
    const float* __restrict__ xres,
    float* __restrict__ out)
{
    __shared__ float sS[192], sH[192];
    __shared__ unsigned short sW[192 * 40];
    const int b   = blockIdx.y;
    const int n0  = blockIdx.x * 64;
    const int tid = threadIdx.x;
    const int wv  = tid >> 6;
    const int l   = tid & 63;
    const int lm  = l & 15, lk = l >> 4;

    if (tid < 192) {
        const float s = gg[tid] * rsqrtf(vv[tid] + 1e-5f);
        sS[tid] = s;
        sH[tid] = (bias[tid] - mm[tid]) * s + bb_[tid];
    }

    const int ncol = n0 + wv * 16 + lm;
    const int ncl  = (ncol < Nn) ? ncol : (Nn - 1);
    const unsigned short* gRow = gT + ((size_t)b * Nn + ncl) * C2c;

    f32x4 acc[12];
#pragma unroll
    for (int mf = 0; mf < 12; ++mf) acc[mf] = (f32x4){0.f, 0.f, 0.f, 0.f};

    const int srow = tid >> 2, spart = tid & 3;
    for (int ks = 0; ks < 12; ++ks) {
        const int k0 = ks * 32;
        bf16x8 bfr = *reinterpret_cast<const bf16x8*>(&gRow[k0 + lk * 8]);
        __syncthreads();
#pragma unroll
        for (int p = 0; p < 3; ++p) {
            const int row = srow + p * 64;
            *reinterpret_cast<bf16x8*>(&sW[row * 40 + spart * 8]) =
                *reinterpret_cast<const bf16x8*>(&wbf[(size_t)row * C2c + k0 + spart * 8]);
        }
        __syncthreads();
#pragma unroll
        for (int mf = 0; mf < 12; ++mf) {
            bf16x8 afr = *reinterpret_cast<const bf16x8*>(&sW[(mf * 16 + lm) * 40 + lk * 8]);
            acc[mf] = __builtin_amdgcn_mfma_f32_16x16x32_bf16(afr, bfr, acc[mf], 0, 0, 0);
        }
    }
    if (ncol < Nn) {
#pragma unroll
        for (int mf = 0; mf < 12; ++mf) {
#pragma unroll
            for (int r = 0; r < 4; ++r) {
                const int o = mf * 16 + lk * 4 + r;   // C/D: row=(l>>4)*4+r
                const size_t oi = ((size_t)b * Cc + o) * Nn + ncol;  // col=lane&15
                out[oi] = fmaf(acc[mf][r], sS[o], sH[o]) + xres[oi];
            }
        }
    }
}

// ---------------------------------------------------------------------------
extern "C" void kernel_launch(void* const* d_in, const int* in_sizes, int n_in,
                              void* d_out, int out_size, void* d_ws, size_t ws_size,
                              hipStream_t stream)
{
    const float* x     = (const float*)d_in[0];
    const float* fc1_w = (const float*)d_in[1];
    const float* fc1_b = (const float*)d_in[2];
    const float* bn1_g = (const float*)d_in[3];
    const float* bn1_b = (const float*)d_in[4];
    const float* bn1_m = (const float*)d_in[5];
    const float* bn1_v = (const float*)d_in[6];
    const float* gc_w  = (const float*)d_in[7];
    const float* gc_b  = (const float*)d_in[8];
    const float* bn2_g = (const float*)d_in[9];
    const float* bn2_b = (const float*)d_in[10];
    const float* bn2_m = (const float*)d_in[11];
    const float* bn2_v = (const float*)d_in[12];
    const float* fc2_w = (const float*)d_in[13];
    const float* fc2_b = (const float*)d_in[14];
    const float* bn3_g = (const float*)d_in[15];
    const float* bn3_b = (const float*)d_in[16];
    const float* bn3_m = (const float*)d_in[17];
    const float* bn3_v = (const float*)d_in[18];

    float* out = (float*)d_out;                  // xt scratch, overwritten by fc2

    // workspace layout (max concurrent ~156 MB):
    //   region A [0, 77.07M):
    //     dist16 [0, 39.34M) (16-batch chunks; dies after last select16)
    //     xnh   [39.34M, 58.61M) (dies after last dist_mfma)
    //     stT   [0, 38.54M) born at mr_pack (over dead dist16)
    //   region B [77.07, 154.14M):
    //     xnT [g2, +38.54M) born at norm_fuse; dies at refine_amb
    //       -> gT (bf16 38.5M, same spot, born at gconv)
    //     sq @ +38.54M | c16 | cd16 (die after refine)
    //     wbf (147KB) @ +45.16M | wbf2 (74KB)
    //     xnl @ +45.38M (19.27M; dies after last dist_mfma)
    //   region C [154.14M, +): nnidx | amb | cnt
    char* wsb = (char*)d_ws;
    const size_t regionBytes = (size_t)Bn * C2c * Nn * 4;    // 77,070,336
    const size_t distBytes   = (size_t)16 * Nn * Nn * 4;     // 39,337,984
    float* dist = (float*)wsb;
    unsigned short* xnh = (unsigned short*)(wsb + distBytes);
    unsigned int*   stT32 = (unsigned int*)wsb;
    unsigned short* stT   = (unsigned short*)wsb;
    char*  g2   = wsb + regionBytes;
    float* xnT  = (float*)g2;                                      // 38,535,168 B
    float* sqb  = (float*)(g2 + (size_t)Bn * Cc * Nn * 4);         // 200,704 B
    int*   c16  = (int*)(g2 + (size_t)Bn * Cc * Nn * 4 + 200704);  // 3,211,264 B
    float* cd16 = (float*)(g2 + (size_t)Bn * Cc * Nn * 4 + 200704 + 3211264); // 3,211,264 B
    unsigned short* gT   = (unsigned short*)g2;                    // bf16, aliases xnT
    unsigned short* wbf  = (unsigned short*)(g2 + 45158912);       // 147,456 B
    unsigned short* wbf2 = (unsigned short*)(g2 + 45158912 + 147456); // 73,728 B
    unsigned short* xnl  = (unsigned short*)(g2 + 45158912 + 147456 + 73728); // 19,267,584 B
    char*  g3   = wsb + 2 * regionBytes;
    int*   nni  = (int*)g3;                                        // 1,806,336 B
    int*   amb  = (int*)(g3 + 1806336);                            // 200,704 B
    int*   cnt  = (int*)(g3 + 1806336 + 200704);                   // 4 B

    const int nBN = Bn * Nn;

    dim3 blk(256);
    wcvt<<<dim3((Cc * C2c + 255) / 256), blk, 0, stream>>>(fc2_w, wbf, Cc * C2c);
    wcvt<<<dim3((4 * 96 * 96 + 255) / 256), blk, 0, stream>>>(gc_w, wbf2, 4 * 96 * 96);
    fc1_np<<<dim3(7, 3, Bn), blk, 0, stream>>>(
        x, fc1_w, fc1_b, bn1_g, bn1_b, bn1_m, bn1_v, out);
    norm_fuse<<<dim3(13, Bn), blk, 0, stream>>>(out, xnh, xnl, xnT, sqb);
    for (int ch = 0; ch < 4; ++ch) {
        dist_mfma<<<dim3(91, 16), blk, 0, stream>>>(xnh, xnl, dist, ch);
        select16<<<dim3(16 * Nn / 4), blk, 0, stream>>>(dist, c16, cd16, ch);
    }
    zero_cnt<<<dim3(1), dim3(64), 0, stream>>>(cnt);
    gap_route<<<dim3((nBN + 255) / 256), blk, 0, stream>>>(c16, cd16, nni, amb, cnt);
    refine_amb<<<dim3(784), blk, 0, stream>>>(xnT, sqb, c16, amb, cnt, nni);
    mr_pack<<<dim3(12, Bn), blk, 0, stream>>>(out, nni, stT32);
    gconv_mfma<<<dim3(13, 4, Bn), blk, 0, stream>>>(
        stT, wbf2, gc_b, bn2_g, bn2_b, bn2_m, bn2_v, gT);
    fc2_mfma<<<dim3(13, Bn), blk, 0, stream>>>(
        gT, wbf, fc2_b, bn3_g, bn3_b, bn3_m, bn3_v, x, out);
}